// Round 14
// baseline (402.645 us; speedup 1.0000x reference)
//
#include <hip/hip_runtime.h>
#include <hip/hip_bf16.h>

#define N_TOK 2048
#define DMODEL 2048
#define NH 16
#define DK 128
#define DFF 8192

typedef __attribute__((ext_vector_type(8))) short short8;
typedef __attribute__((ext_vector_type(4))) short s16x4;
typedef __attribute__((ext_vector_type(4))) float f32x4;

__device__ __forceinline__ short f2bf(float f) {
    unsigned int x = __builtin_bit_cast(unsigned int, f);
    unsigned int r = (x + 0x7fffu + ((x >> 16) & 1u)) >> 16;
    return (short)r;
}
__device__ __forceinline__ float bf2f(short s) {
    unsigned int u = ((unsigned int)(unsigned short)s) << 16;
    return __builtin_bit_cast(float, u);
}

// ---------------- cast X (f32 -> bf16), 8 elems/thread ----------------
__global__ __launch_bounds__(256) void cast_f32_bf16(const float* __restrict__ in,
                                                     short* __restrict__ out, int n8) {
    int i = blockIdx.x * 256 + threadIdx.x;
    if (i >= n8) return;
    const float4* p = (const float4*)in + (size_t)i * 2;
    float4 a = p[0], b = p[1];
    short8 o;
    o[0] = f2bf(a.x); o[1] = f2bf(a.y); o[2] = f2bf(a.z); o[3] = f2bf(a.w);
    o[4] = f2bf(b.x); o[5] = f2bf(b.y); o[6] = f2bf(b.z); o[7] = f2bf(b.w);
    *(short8*)(out + (size_t)i * 8) = o;
}

// --- transpose + cast to bf16 (64x64 LDS tiles, 16B reads + short8 writes) --
template <typename TIN>
__global__ __launch_bounds__(256) void transpose_cast(const TIN* __restrict__ in,
                                                      short* __restrict__ out,
                                                      int R, int C, long sIn, long sOut) {
    __shared__ float t[64][65];
    in  += (long)blockIdx.z * sIn;
    out += (long)blockIdx.z * sOut;
    const int tid = threadIdx.x;
    long r0 = (long)blockIdx.y * 64, c0 = (long)blockIdx.x * 64;
    if constexpr (sizeof(TIN) == 4) {
#pragma unroll
        for (int i = 0; i < 4; i++) {
            int r = (tid >> 4) + i * 16;
            int c = (tid & 15) * 4;
            float4 v = *(const float4*)((const float*)in + (r0 + r) * (long)C + c0 + c);
            t[r][c + 0] = v.x; t[r][c + 1] = v.y; t[r][c + 2] = v.z; t[r][c + 3] = v.w;
        }
    } else {
#pragma unroll
        for (int i = 0; i < 2; i++) {
            int r = (tid >> 3) + i * 32;
            int c = (tid & 7) * 8;
            short8 v = *(const short8*)((const short*)in + (r0 + r) * (long)C + c0 + c);
#pragma unroll
            for (int j = 0; j < 8; j++) t[r][c + j] = bf2f(v[j]);
        }
    }
    __syncthreads();
#pragma unroll
    for (int p = 0; p < 2; p++) {
        int c = (tid >> 3) + p * 32;
        int r8 = (tid & 7) * 8;
        short8 v;
#pragma unroll
        for (int j = 0; j < 8; j++) v[j] = f2bf(t[r8 + j][c]);
        *(short8*)(out + (c0 + c) * (long)R + r0 + r8) = v;
    }
}

// ---------------- async global->LDS helper ----------------
__device__ __forceinline__ void gld_lds16(const void* g, void* l) {
    __builtin_amdgcn_global_load_lds(
        (const __attribute__((address_space(1))) void*)g,
        (__attribute__((address_space(3))) void*)l, 16, 0, 0);
}

// ===== 256x128 bf16 GEMM, BK=32, 4 waves, single-buffer, 2 blocks/CU ========
// m97/m114 mechanism: small LDS (24KB) + 256 threads -> 2 blocks co-resident
// per CU; their stage/barrier phases overlap the other block's MFMA phase
// (inter-block, no sync). Swizzle: granule ^ ((row>>1)&3) (R8-verified, 0
// conflicts at BK=32); staging carries the inverse on the GLOBAL source.
// MODE 0: QKV fused N=6144, bias per 2048-col group, bf16 slab output
// MODE 1: FFN1 N=8192, +bias, ReLU, bf16
// MODE 2: FFN2 split-K slab z (Kloop=2048 of 8192), bf16 slab output
template <int MODE>
__global__ __launch_bounds__(256, 2) void gemm_cr(const short* __restrict__ A,
                                                  const short* __restrict__ Bt,
                                                  void* __restrict__ Cv,
                                                  const float* __restrict__ b0,
                                                  const float* __restrict__ b1,
                                                  const float* __restrict__ b2,
                                                  int Ktot, int TM) {
    __shared__ short lds[12288];   // 24 KB: A[256][32] | B[128][32]
    const int tid = threadIdx.x, lane = tid & 63, w = tid >> 6;
    const int T = gridDim.x, bid = blockIdx.x;
    const int vbid = (bid & 7) * (T >> 3) + (bid >> 3);   // XCD chunking
    const int mt = vbid % TM;
    const int rest = vbid / TM;
    int nt = rest, z = 0;
    if (MODE == 2) { nt = rest & 15; z = rest >> 4; }
    const long brow = (long)mt * 256, bcol = (long)nt * 128;
    const short* Ab = A + (MODE == 2 ? (long)z * 2048 : 0);
    const short* Bb = Bt + (MODE == 2 ? (long)z * 2048 : 0);

    auto stage = [&](int kt) {
        const long k0 = (long)kt * 32;
#pragma unroll
        for (int i = 0; i < 4; i++) {
            int a = i * 4096 + tid * 16;
            int row = a >> 6;
            int colb = (a & 63) ^ (((row >> 1) & 3) << 4);
            gld_lds16((const char*)(Ab + (brow + row) * (long)Ktot + k0) + colb,
                      (char*)lds + a);
        }
#pragma unroll
        for (int i = 0; i < 2; i++) {
            int a = i * 4096 + tid * 16;
            int row = a >> 6;
            int colb = (a & 63) ^ (((row >> 1) & 3) << 4);
            gld_lds16((const char*)(Bb + (bcol + row) * (long)Ktot + k0) + colb,
                      (char*)lds + 16384 + a);
        }
    };

    const int wr = w >> 1, wc = w & 1;          // 2 x 2 wave grid (128 x 64 out)
    const int fr = lane & 15, fq = lane >> 4;
    const int fcol = (fq * 16) ^ (((fr >> 1) & 3) << 4);
    f32x4 acc[8][4] = {};

    const int NT = 2048 / 32;   // 64 (Kloop = 2048 in all modes)
    for (int t = 0; t < NT; t++) {
        stage(t);
        __syncthreads();        // vmcnt(0) drain; overlapped by the CO-RESIDENT block
        short8 af[8], bf[4];
#pragma unroll
        for (int m = 0; m < 8; m++)
            af[m] = *(const short8*)((const char*)lds + (wr * 128 + m * 16 + fr) * 64 + fcol);
#pragma unroll
        for (int n = 0; n < 4; n++)
            bf[n] = *(const short8*)((const char*)lds + 16384 + (wc * 64 + n * 16 + fr) * 64 + fcol);
        __builtin_amdgcn_s_setprio(1);
#pragma unroll
        for (int m = 0; m < 8; m++)
#pragma unroll
            for (int n = 0; n < 4; n++)
                acc[m][n] = __builtin_amdgcn_mfma_f32_16x16x32_bf16(af[m], bf[n], acc[m][n], 0, 0, 0);
        __builtin_amdgcn_s_setprio(0);
        __syncthreads();
    }

    const long crow0 = brow + wr * 128, ccol0 = bcol + wc * 64;
#pragma unroll
    for (int n = 0; n < 4; n++) {
        const long col = ccol0 + n * 16 + fr;
        float bval = 0.f;
        if (MODE == 0) {
            const float* bp = (col >> 11) == 0 ? b0 : (col >> 11) == 1 ? b1 : b2;
            bval = bp[col & 2047];
        } else if (MODE == 1) bval = b0[col];
#pragma unroll
        for (int m = 0; m < 8; m++) {
#pragma unroll
            for (int r = 0; r < 4; r++) {
                const long row = crow0 + m * 16 + fq * 4 + r;
                float v = acc[m][n][r] + bval;
                if (MODE == 0) {
                    const long slab = col >> 7;
                    ((short*)Cv)[slab * (2048L * 128) + row * 128 + (col & 127)] = f2bf(v);
                } else if (MODE == 1) {
                    ((short*)Cv)[row * 8192 + col] = f2bf(fmaxf(v, 0.f));
                } else {
                    ((short*)Cv)[(long)z * (2048L * 2048) + row * 2048 + col] = f2bf(v);
                }
            }
        }
    }
}

// ------- flash attention v6: 4-deep K/V rings, 1 barrier/iter, vmcnt(8) -----
__global__ __launch_bounds__(512, 2) void attn_flash(const short* __restrict__ Q,
                                                     const short* __restrict__ Kc,
                                                     const short* __restrict__ VT,
                                                     float* __restrict__ O) {
    __shared__ short lds[73728];   // 144 KB
    const int tid = threadIdx.x, lane = tid & 63, w = tid >> 6;
    const int bid = blockIdx.x;
    const int vid = (bid & 7) * 32 + (bid >> 3);   // XCD-chunked swizzle
    const int h = vid >> 4, qt = vid & 15;
    const int fr = lane & 15, fq = lane >> 4;
    const long qbase = (long)qt * 128 + w * 16;
    const short* Qh = Q  + (long)h * N_TOK * DK;
    const short* Kh = Kc + (long)h * N_TOK * DK;
    const short* Vh = VT + (long)h * DK * N_TOK;
    short* Pw = lds + 65536 + w * 1024;

    short8 qf[4];
#pragma unroll
    for (int c = 0; c < 4; c++)
        qf[c] = *(const short8*)(Qh + (qbase + fr) * DK + c * 32 + fq * 8);

    float mrow = -1e30f, lrow = 0.f;
    f32x4 oacc[8] = {};
    const float C1 = 0.08838834764831845f * 1.4426950408889634f; // 1/sqrt(128)*log2e

    int wr_off[4], rd_off[2];
#pragma unroll
    for (int jc = 0; jc < 4; jc++)
        wr_off[jc] = (fr * 64 + jc * 16 + fq * 4) ^ ((fr & 7) << 3);
#pragma unroll
    for (int kc = 0; kc < 2; kc++)
        rd_off[kc] = (fr * 64 + kc * 32 + fq * 8) ^ ((fr & 7) << 3);
    int colKb[4], colVb[2];
#pragma unroll
    for (int c = 0; c < 4; c++) colKb[c] = (c * 64 + fq * 16) ^ ((fr & 7) << 4);
#pragma unroll
    for (int kc = 0; kc < 2; kc++) colVb[kc] = (kc * 64 + fq * 16) ^ ((fr & 7) << 4);

    auto stageK = [&](int kvt) {
        const int buf = kvt & 3;
        const char* Kg = (const char*)(Kh + (long)kvt * 64 * DK);
        char* Kd = (char*)lds + buf * 16384;
#pragma unroll
        for (int i = 0; i < 2; i++) {
            int a = (w * 2 + i) * 1024 + (lane << 4);
            int src = a ^ (((a >> 8) & 7) << 4);
            gld_lds16(Kg + src, Kd + (w * 2 + i) * 1024);
        }
    };
    auto stageV = [&](int kvt) {
        const int buf = kvt & 3;
        char* Vd = (char*)lds + 65536 + buf * 16384;
#pragma unroll
        for (int i = 0; i < 2; i++) {
            int a = (w * 2 + i) * 1024 + (lane << 4);
            int row = a >> 7;
            int inner = (a & 127) ^ ((row & 7) << 4);
            const char* src = (const char*)Vh + ((long)row * N_TOK + (long)kvt * 64) * 2 + inner;
            gld_lds16(src, Vd + (w * 2 + i) * 1024);
        }
    };

    const int NT = N_TOK / 64;   // 32
    stageK(0); stageV(0); stageK(1); stageV(1); stageK(2); stageV(2); stageK(3);
    asm volatile("s_waitcnt vmcnt(12)" ::: "memory");
    __builtin_amdgcn_s_barrier();
    __builtin_amdgcn_sched_barrier(0);

    for (int t = 0; t < NT; t++) {
        const char* Kcb = (const char*)lds + (t & 3) * 16384;
        f32x4 s[4] = {};
#pragma unroll
        for (int jc = 0; jc < 4; jc++) {
            const char* rb = Kcb + (jc * 16 + fr) * 256;
#pragma unroll
            for (int c = 0; c < 4; c++) {
                short8 kf = *(const short8*)(rb + colKb[c]);
                s[jc] = __builtin_amdgcn_mfma_f32_16x16x32_bf16(kf, qf[c], s[jc], 0, 0, 0);
            }
        }

        float tm = -1e30f;
#pragma unroll
        for (int jc = 0; jc < 4; jc++)
#pragma unroll
            for (int r = 0; r < 4; r++) tm = fmaxf(tm, s[jc][r]);
        tm = fmaxf(tm, __shfl_xor(tm, 16));
        tm = fmaxf(tm, __shfl_xor(tm, 32));
        float nm = fmaxf(mrow, tm);
        float resc = exp2f(C1 * (mrow - nm));
        mrow = nm;
        float sum = 0.f;
#pragma unroll
        for (int jc = 0; jc < 4; jc++)
#pragma unroll
            for (int r = 0; r < 4; r++) {
                float p = exp2f(C1 * (s[jc][r] - nm));
                s[jc][r] = p;
                sum += p;
            }
        sum += __shfl_xor(sum, 16);
        sum += __shfl_xor(sum, 32);
        lrow = lrow * resc + sum;
#pragma unroll
        for (int f = 0; f < 8; f++)
#pragma unroll
            for (int r = 0; r < 4; r++) oacc[f][r] *= resc;

#pragma unroll
        for (int jc = 0; jc < 4; jc++) {
            s16x4 pk;
            pk[0] = f2bf(s[jc][0]); pk[1] = f2bf(s[jc][1]);
            pk[2] = f2bf(s[jc][2]); pk[3] = f2bf(s[jc][3]);
            *(s16x4*)(Pw + wr_off[jc]) = pk;
        }
        short8 pa[2];
#pragma unroll
        for (int kc = 0; kc < 2; kc++)
            pa[kc] = *(const short8*)(Pw + rd_off[kc]);

        if (t < NT - 4) asm volatile("s_waitcnt vmcnt(8)" ::: "memory");
        else            asm volatile("s_waitcnt vmcnt(0)" ::: "memory");
        __builtin_amdgcn_sched_barrier(0);
        __builtin_amdgcn_s_barrier();
        __builtin_amdgcn_sched_barrier(0);

        const char* Vcb = (const char*)lds + 65536 + (t & 3) * 16384;
#pragma unroll
        for (int f = 0; f < 8; f++) {
            const char* rb = Vcb + (f * 16 + fr) * 128;
#pragma unroll
            for (int kc = 0; kc < 2; kc++) {
                short8 vf = *(const short8*)(rb + colVb[kc]);
                oacc[f] = __builtin_amdgcn_mfma_f32_16x16x32_bf16(vf, pa[kc], oacc[f], 0, 0, 0);
            }
        }

        if (t + 4 < NT) stageK(t + 4);
        if (t + 3 < NT) stageV(t + 3);
    }

    const float inv = 1.f / lrow;
    const long row = qbase + fr;
#pragma unroll
    for (int f = 0; f < 8; f++) {
        float4 o;
        o.x = oacc[f][0] * inv; o.y = oacc[f][1] * inv;
        o.z = oacc[f][2] * inv; o.w = oacc[f][3] * inv;
        *(float4*)(O + row * (long)DMODEL + h * DK + f * 16 + fq * 4) = o;
    }
}

// ---------------- fused Add + LayerNorm (1 block = 1 row of 2048) -----------
template <bool WBF>
__global__ __launch_bounds__(256) void add_ln(const float* __restrict__ A,
                                              const float* __restrict__ B,
                                              const float* __restrict__ alpha,
                                              const float* __restrict__ beta,
                                              float* __restrict__ out,
                                              short* __restrict__ outbf) {
    const int row = blockIdx.x, t = threadIdx.x;
    const long base = (long)row * DMODEL;
    float4 va[2], vb[2];
    float s = 0.f, q = 0.f;
#pragma unroll
    for (int i = 0; i < 2; i++) {
        long off = base + (long)(t + i * 256) * 4;
        va[i] = *(const float4*)(A + off);
        vb[i] = *(const float4*)(B + off);
        float x0 = va[i].x + vb[i].x, x1 = va[i].y + vb[i].y;
        float x2 = va[i].z + vb[i].z, x3 = va[i].w + vb[i].w;
        s += x0 + x1 + x2 + x3;
        q += x0 * x0 + x1 * x1 + x2 * x2 + x3 * x3;
    }
#pragma unroll
    for (int o = 1; o < 64; o <<= 1) { s += __shfl_xor(s, o); q += __shfl_xor(q, o); }
    __shared__ float red[8];
    if ((t & 63) == 0) { red[t >> 6] = s; red[4 + (t >> 6)] = q; }
    __syncthreads();
    s = red[0] + red[1] + red[2] + red[3];
    q = red[4] + red[5] + red[6] + red[7];
    const float mean = s * (1.f / DMODEL);
    const float var = q * (1.f / DMODEL) - mean * mean;
    const float rstd = rsqrtf(var + 1e-5f);
#pragma unroll
    for (int i = 0; i < 2; i++) {
        long off = base + (long)(t + i * 256) * 4;
        float4 al = *(const float4*)(alpha + off);
        float4 be = *(const float4*)(beta + off);
        float x[4] = { va[i].x + vb[i].x, va[i].y + vb[i].y, va[i].z + vb[i].z, va[i].w + vb[i].w };
        float a[4] = { al.x, al.y, al.z, al.w };
        float b[4] = { be.x, be.y, be.z, be.w };
#pragma unroll
        for (int j = 0; j < 4; j++) {
            float o2 = (x[j] - mean) * rstd * a[j] + b[j];
            out[off + j] = o2;
            if (WBF) outbf[off + j] = f2bf(o2);
        }
    }
}

// -------- Add + LN2 with 4-slab (bf16) split-K reduction + bias -------------
__global__ __launch_bounds__(256) void add_ln2_red(const float* __restrict__ H1,
                                                   const short* __restrict__ F4,
                                                   const float* __restrict__ b2,
                                                   const float* __restrict__ alpha,
                                                   const float* __restrict__ beta,
                                                   float* __restrict__ out) {
    const int row = blockIdx.x, t = threadIdx.x;
    const long base = (long)row * DMODEL;
    const long SL = (long)N_TOK * DMODEL;
    float x[8];
    float s = 0.f, q = 0.f;
#pragma unroll
    for (int i = 0; i < 2; i++) {
        long off = base + (long)(t + i * 256) * 4;
        int col = (t + i * 256) * 4;
        float4 a  = *(const float4*)(H1 + off);
        s16x4 f0 = *(const s16x4*)(F4 + off);
        s16x4 f1 = *(const s16x4*)(F4 + off + SL);
        s16x4 f2 = *(const s16x4*)(F4 + off + 2 * SL);
        s16x4 f3 = *(const s16x4*)(F4 + off + 3 * SL);
        float4 bb = *(const float4*)(b2 + col);
        float xa[4] = { a.x + bb.x, a.y + bb.y, a.z + bb.z, a.w + bb.w };
#pragma unroll
        for (int j = 0; j < 4; j++) {
            float v = xa[j] + bf2f(f0[j]) + bf2f(f1[j]) + bf2f(f2[j]) + bf2f(f3[j]);
            x[i * 4 + j] = v;
            s += v; q += v * v;
        }
    }
#pragma unroll
    for (int o = 1; o < 64; o <<= 1) { s += __shfl_xor(s, o); q += __shfl_xor(q, o); }
    __shared__ float red[8];
    if ((t & 63) == 0) { red[t >> 6] = s; red[4 + (t >> 6)] = q; }
    __syncthreads();
    s = red[0] + red[1] + red[2] + red[3];
    q = red[4] + red[5] + red[6] + red[7];
    const float mean = s * (1.f / DMODEL);
    const float var = q * (1.f / DMODEL) - mean * mean;
    const float rstd = rsqrtf(var + 1e-5f);
#pragma unroll
    for (int i = 0; i < 2; i++) {
        long off = base + (long)(t + i * 256) * 4;
        float4 al = *(const float4*)(alpha + off);
        float4 be = *(const float4*)(beta + off);
        float a[4] = { al.x, al.y, al.z, al.w };
        float b[4] = { be.x, be.y, be.z, be.w };
#pragma unroll
        for (int j = 0; j < 4; j++)
            out[off + j] = (x[i * 4 + j] - mean) * rstd * a[j] + b[j];
    }
}

extern "C" void kernel_launch(void* const* d_in, const int* in_sizes, int n_in,
                              void* d_out, int out_size, void* d_ws, size_t ws_size,
                              hipStream_t stream) {
    const float* X      = (const float*)d_in[0];
    const float* Wq     = (const float*)d_in[1];
    const float* bq     = (const float*)d_in[2];
    const float* Wk     = (const float*)d_in[3];
    const float* bk     = (const float*)d_in[4];
    const float* Wv     = (const float*)d_in[5];
    const float* bv     = (const float*)d_in[6];
    const float* alpha1 = (const float*)d_in[7];
    const float* beta1  = (const float*)d_in[8];
    const float* W1     = (const float*)d_in[9];
    const float* b1     = (const float*)d_in[10];
    const float* W2     = (const float*)d_in[11];
    const float* b2     = (const float*)d_in[12];
    const float* alpha2 = (const float*)d_in[13];
    const float* beta2  = (const float*)d_in[14];
    float* out = (float*)d_out;

    char* ws = (char*)d_ws;
    size_t off = 0;
    auto alloc = [&](size_t bytes) -> void* {
        void* p = ws + off;
        off += (bytes + 255) & ~(size_t)255;
        return p;
    };
    short* XBF   = (short*)alloc(2048UL * 2048 * 2);       // dead after QKV gemm
    short* WQKVT = (short*)alloc(48UL * 128 * 2048 * 2);   // = [6144][2048]; dead after QKV
    short* W1T   = (short*)alloc(8192UL * 2048 * 2);       // dead after FFN1
    short* W2T   = (short*)alloc(2048UL * 8192 * 2);
    short* QKV   = (short*)alloc(48UL * 2048 * 128 * 2);   // Q(0-15),K(16-31),V(32-47)
    short* VT    = (short*)alloc(16UL * 128 * 2048 * 2);
    float* ATTN  = (float*)alloc(2048UL * 2048 * 4);
    float* H1    = (float*)alloc(2048UL * 2048 * 4);
    short* H1BF  = (short*)alloc(2048UL * 2048 * 2);
    short* G     = (short*)alloc(2048UL * 8192 * 2);
    // F4 (32 MB, 4 bf16 split-K slabs) aliases XBF+WQKVT (dead by FFN2)
    short* F4 = XBF;

    // 1. casts / transposes
    cast_f32_bf16<<<2048, 256, 0, stream>>>(X, XBF, 2048 * 2048 / 8);
    transpose_cast<float><<<dim3(2, 32, 16), 256, 0, stream>>>(Wq, WQKVT,                    2048, 128, 2048L * 128, 128L * 2048);
    transpose_cast<float><<<dim3(2, 32, 16), 256, 0, stream>>>(Wk, WQKVT + 16L * 128 * 2048, 2048, 128, 2048L * 128, 128L * 2048);
    transpose_cast<float><<<dim3(2, 32, 16), 256, 0, stream>>>(Wv, WQKVT + 32L * 128 * 2048, 2048, 128, 2048L * 128, 128L * 2048);
    transpose_cast<float><<<dim3(128, 32, 1), 256, 0, stream>>>(W1, W1T, 2048, 8192, 0, 0);
    transpose_cast<float><<<dim3(32, 128, 1), 256, 0, stream>>>(W2, W2T, 8192, 2048, 0, 0);

    // 2. QKV fused GEMM: M=2048, N=6144 (TM=8 x TN=48 -> 384 blocks)
    gemm_cr<0><<<384, 256, 0, stream>>>(XBF, WQKVT, QKV, bq, bk, bv, 2048, 8);

    // 3. V -> V^T per head
    transpose_cast<__hip_bfloat16><<<dim3(2, 32, 16), 256, 0, stream>>>(
        (const __hip_bfloat16*)(QKV + 32L * 2048 * 128), VT, 2048, 128, 2048L * 128, 128L * 2048);

    // 4. attention (256 blocks x 8 waves; 4-deep pipelined K/V)
    attn_flash<<<256, 512, 0, stream>>>(QKV, QKV + 16L * 2048 * 128, VT, ATTN);

    // 5. Add & LN 1
    add_ln<true><<<2048, 256, 0, stream>>>(X, ATTN, alpha1, beta1, H1, H1BF);

    // 6. FFN: FFN1 (8x64=512 blocks); FFN2 split-K=4 (8x16x4=512 blocks)
    gemm_cr<1><<<512, 256, 0, stream>>>(H1BF, W1T, G, b1, nullptr, nullptr, 2048, 8);
    gemm_cr<2><<<512, 256, 0, stream>>>(G, W2T, F4, nullptr, nullptr, nullptr, 8192, 8);

    // 7. Add + reduce + LN 2 -> output
    add_ln2_red<<<2048, 256, 0, stream>>>(H1, F4, b2, alpha2, beta2, out);
}

// Round 15
// 364.435 us; speedup vs baseline: 1.1048x; 1.1048x over previous
//
#include <hip/hip_runtime.h>
#include <hip/hip_bf16.h>

#define N_TOK 2048
#define DMODEL 2048
#define NH 16
#define DK 128
#define DFF 8192

typedef __attribute__((ext_vector_type(8))) short short8;
typedef __attribute__((ext_vector_type(4))) short s16x4;
typedef __attribute__((ext_vector_type(4))) float f32x4;

__device__ __forceinline__ short f2bf(float f) {
    unsigned int x = __builtin_bit_cast(unsigned int, f);
    unsigned int r = (x + 0x7fffu + ((x >> 16) & 1u)) >> 16;
    return (short)r;
}
__device__ __forceinline__ float bf2f(short s) {
    unsigned int u = ((unsigned int)(unsigned short)s) << 16;
    return __builtin_bit_cast(float, u);
}

// ---------------- cast X (f32 -> bf16), 8 elems/thread ----------------
__global__ __launch_bounds__(256) void cast_f32_bf16(const float* __restrict__ in,
                                                     short* __restrict__ out, int n8) {
    int i = blockIdx.x * 256 + threadIdx.x;
    if (i >= n8) return;
    const float4* p = (const float4*)in + (size_t)i * 2;
    float4 a = p[0], b = p[1];
    short8 o;
    o[0] = f2bf(a.x); o[1] = f2bf(a.y); o[2] = f2bf(a.z); o[3] = f2bf(a.w);
    o[4] = f2bf(b.x); o[5] = f2bf(b.y); o[6] = f2bf(b.z); o[7] = f2bf(b.w);
    *(short8*)(out + (size_t)i * 8) = o;
}

// --- transpose + cast to bf16 (64x64 LDS tiles, 16B reads + short8 writes) --
template <typename TIN>
__global__ __launch_bounds__(256) void transpose_cast(const TIN* __restrict__ in,
                                                      short* __restrict__ out,
                                                      int R, int C, long sIn, long sOut) {
    __shared__ float t[64][65];
    in  += (long)blockIdx.z * sIn;
    out += (long)blockIdx.z * sOut;
    const int tid = threadIdx.x;
    long r0 = (long)blockIdx.y * 64, c0 = (long)blockIdx.x * 64;
    if constexpr (sizeof(TIN) == 4) {
#pragma unroll
        for (int i = 0; i < 4; i++) {
            int r = (tid >> 4) + i * 16;
            int c = (tid & 15) * 4;
            float4 v = *(const float4*)((const float*)in + (r0 + r) * (long)C + c0 + c);
            t[r][c + 0] = v.x; t[r][c + 1] = v.y; t[r][c + 2] = v.z; t[r][c + 3] = v.w;
        }
    } else {
#pragma unroll
        for (int i = 0; i < 2; i++) {
            int r = (tid >> 3) + i * 32;
            int c = (tid & 7) * 8;
            short8 v = *(const short8*)((const short*)in + (r0 + r) * (long)C + c0 + c);
#pragma unroll
            for (int j = 0; j < 8; j++) t[r][c + j] = bf2f(v[j]);
        }
    }
    __syncthreads();
#pragma unroll
    for (int p = 0; p < 2; p++) {
        int c = (tid >> 3) + p * 32;
        int r8 = (tid & 7) * 8;
        short8 v;
#pragma unroll
        for (int j = 0; j < 8; j++) v[j] = f2bf(t[r8 + j][c]);
        *(short8*)(out + (c0 + c) * (long)R + r0 + r8) = v;
    }
}

// ---------------- async global->LDS helper ----------------
__device__ __forceinline__ void gld_lds16(const void* g, void* l) {
    __builtin_amdgcn_global_load_lds(
        (const __attribute__((address_space(1))) void*)g,
        (__attribute__((address_space(3))) void*)l, 16, 0, 0);
}

// ======== 256x256 bf16 GEMM, BK=64, 8 waves, 8-phase, B-read-once ===========
// (R13 configuration — best measured; plateaued ~830 TF at this shape)
#define VM8 asm volatile("s_waitcnt vmcnt(8)" ::: "memory")
#define VM0 asm volatile("s_waitcnt vmcnt(0)" ::: "memory")
#define VMNONE ((void)0)

#define PHASE(BUF, MH, NHI, RA, RBNH, STAGE_STMT, VMSTMT)                       \
  {                                                                             \
    if (RA) {                                                                   \
      _Pragma("unroll") for (int mp = 0; mp < 4; mp++)                          \
        _Pragma("unroll") for (int kk = 0; kk < 2; kk++) {                      \
          int rowA = wr * 128 + (MH) * 64 + mp * 16 + fr;                       \
          af[mp][kk] = *(const short8*)((const char*)lds + (BUF) * 65536 +      \
                         rowA * 128 + (((kk * 4 + fq) ^ (rowA & 7)) << 4));     \
        }                                                                       \
    }                                                                           \
    if ((RBNH) < 2) {                                                           \
      _Pragma("unroll") for (int np = 0; np < 2; np++)                          \
        _Pragma("unroll") for (int kk = 0; kk < 2; kk++) {                      \
          int rowB = wc * 64 + (RBNH) * 32 + np * 16 + fr;                      \
          bf[(RBNH) & 1][np][kk] =                                              \
              *(const short8*)((const char*)lds + (BUF) * 65536 + 32768 +       \
                  rowB * 128 + (((kk * 4 + fq) ^ (rowB & 7)) << 4));            \
        }                                                                       \
    }                                                                           \
    STAGE_STMT;                                                                 \
    __builtin_amdgcn_s_barrier();                                               \
    __builtin_amdgcn_s_setprio(1);                                              \
    _Pragma("unroll") for (int mp = 0; mp < 4; mp++)                            \
      _Pragma("unroll") for (int np = 0; np < 2; np++)                          \
        _Pragma("unroll") for (int kk = 0; kk < 2; kk++)                        \
          acc[(MH) * 4 + mp][(NHI) * 2 + np] =                                  \
              __builtin_amdgcn_mfma_f32_16x16x32_bf16(                          \
                  af[mp][kk], bf[NHI][np][kk], acc[(MH) * 4 + mp][(NHI) * 2 + np],\
                  0, 0, 0);                                                     \
    __builtin_amdgcn_s_setprio(0);                                              \
    VMSTMT;                                                                     \
    __builtin_amdgcn_s_barrier();                                               \
  }

template <int MODE>
__global__ __launch_bounds__(512, 2) void gemm256(const short* __restrict__ A,
                                                  const short* __restrict__ Bt,
                                                  void* __restrict__ Cv,
                                                  const float* __restrict__ b0,
                                                  const float* __restrict__ b1,
                                                  const float* __restrict__ b2,
                                                  int Ktot, int TM) {
    __shared__ short lds[65536];   // 128 KB
    const int tid = threadIdx.x, lane = tid & 63, w = tid >> 6;
    const int T = gridDim.x, bid = blockIdx.x;
    const int vbid = (bid & 7) * (T >> 3) + (bid >> 3);   // XCD chunking
    const int mt = vbid % TM;
    const int rest = vbid / TM;
    int nt = rest, z = 0;
    if (MODE == 2) { nt = rest & 7; z = rest >> 3; }
    const long brow = (long)mt * 256, bcol = (long)nt * 256;
    const short* Ab = A + (MODE == 2 ? (long)z * 2048 : 0);
    const short* Bb = Bt + (MODE == 2 ? (long)z * 2048 : 0);

    auto stageA = [&](int kt, int buf, int mh) {
#pragma unroll
        for (int j = 0; j < 2; j++) {
            int row = mh * 64 + j * 128 + (tid >> 3);
            int g = (lane & 7) ^ (row & 7);
            gld_lds16((const char*)(Ab + (brow + row) * (long)Ktot + (long)kt * 64) + g * 16,
                      (char*)lds + buf * 65536 + mh * 8192 + j * 16384 + w * 1024 + lane * 16);
        }
    };
    auto stageB = [&](int kt, int buf, int nh) {
#pragma unroll
        for (int j = 0; j < 2; j++) {
            int s = 2 * j + (w >> 2);
            int rin = (w & 3) * 8 + (lane >> 3);
            int row = s * 64 + nh * 32 + rin;
            int g = (lane & 7) ^ (row & 7);
            gld_lds16((const char*)(Bb + (bcol + row) * (long)Ktot + (long)kt * 64) + g * 16,
                      (char*)lds + buf * 65536 + 32768 + j * 16384 + (w >> 2) * 8192 +
                          nh * 4096 + (w & 3) * 1024 + lane * 16);
        }
    };

    const int wr = w >> 2, wc = w & 3;          // 2 x 4 wave grid (128 x 64 out)
    const int fr = lane & 15, fq = lane >> 4;
    f32x4 acc[8][4] = {};
    short8 af[4][2], bf[2][2][2];

    stageA(0, 0, 0); stageB(0, 0, 0); stageB(0, 0, 1); stageA(0, 0, 1);
    stageA(1, 1, 0); stageB(1, 1, 0); stageB(1, 1, 1); stageA(1, 1, 1);
    VM8;
    __builtin_amdgcn_s_barrier();

    for (int i = 0; i < 15; i++) {
        const int kn = 2 * i + 2;
        PHASE(0, 0, 0, 1, 0, {}, VMNONE)
        PHASE(0, 0, 1, 0, 1, { stageA(kn, 0, 0); stageB(kn, 0, 0); }, VMNONE)
        PHASE(0, 1, 0, 1, 2, { stageB(kn, 0, 1); }, VMNONE)
        PHASE(0, 1, 1, 0, 2, { stageA(kn, 0, 1); }, VM8)
        PHASE(1, 0, 0, 1, 0, {}, VMNONE)
        PHASE(1, 0, 1, 0, 1, { stageA(kn + 1, 1, 0); stageB(kn + 1, 1, 0); }, VMNONE)
        PHASE(1, 1, 0, 1, 2, { stageB(kn + 1, 1, 1); }, VMNONE)
        PHASE(1, 1, 1, 0, 2, { stageA(kn + 1, 1, 1); }, VM8)
    }
    PHASE(0, 0, 0, 1, 0, {}, VMNONE)
    PHASE(0, 0, 1, 0, 1, {}, VMNONE)
    PHASE(0, 1, 0, 1, 2, {}, VMNONE)
    PHASE(0, 1, 1, 0, 2, {}, VM0)
    PHASE(1, 0, 0, 1, 0, {}, VMNONE)
    PHASE(1, 0, 1, 0, 1, {}, VMNONE)
    PHASE(1, 1, 0, 1, 2, {}, VMNONE)
    PHASE(1, 1, 1, 0, 2, {}, VMNONE)

    const long crow0 = brow + wr * 128, ccol0 = bcol + wc * 64;
#pragma unroll
    for (int n = 0; n < 4; n++) {
        const long col = ccol0 + (n >> 1) * 32 + (n & 1) * 16 + fr;
        float bval = 0.f;
        if (MODE == 0) {
            const float* bp = (col >> 11) == 0 ? b0 : (col >> 11) == 1 ? b1 : b2;
            bval = bp[col & 2047];
        } else if (MODE == 1) bval = b0[col];
#pragma unroll
        for (int m = 0; m < 8; m++) {
#pragma unroll
            for (int r = 0; r < 4; r++) {
                const long row = crow0 + (m >> 2) * 64 + (m & 3) * 16 + fq * 4 + r;
                float v = acc[m][n][r] + bval;
                if (MODE == 0) {
                    const long slab = col >> 7;
                    ((short*)Cv)[slab * (2048L * 128) + row * 128 + (col & 127)] = f2bf(v);
                } else if (MODE == 1) {
                    ((short*)Cv)[row * 8192 + col] = f2bf(fmaxf(v, 0.f));
                } else {
                    ((short*)Cv)[(long)z * (2048L * 2048) + row * 2048 + col] = f2bf(v);
                }
            }
        }
    }
}

// ------- flash attention v7: 4-deep rings + defer-max + bf16 output ---------
__global__ __launch_bounds__(512, 2) void attn_flash(const short* __restrict__ Q,
                                                     const short* __restrict__ Kc,
                                                     const short* __restrict__ VT,
                                                     short* __restrict__ O) {
    __shared__ short lds[73728];   // 144 KB
    const int tid = threadIdx.x, lane = tid & 63, w = tid >> 6;
    const int bid = blockIdx.x;
    const int vid = (bid & 7) * 32 + (bid >> 3);   // XCD-chunked swizzle
    const int h = vid >> 4, qt = vid & 15;
    const int fr = lane & 15, fq = lane >> 4;
    const long qbase = (long)qt * 128 + w * 16;
    const short* Qh = Q  + (long)h * N_TOK * DK;
    const short* Kh = Kc + (long)h * N_TOK * DK;
    const short* Vh = VT + (long)h * DK * N_TOK;
    short* Pw = lds + 65536 + w * 1024;

    short8 qf[4];
#pragma unroll
    for (int c = 0; c < 4; c++)
        qf[c] = *(const short8*)(Qh + (qbase + fr) * DK + c * 32 + fq * 8);

    float mrow = -1e30f, lrow = 0.f;
    f32x4 oacc[8] = {};
    const float C1 = 0.08838834764831845f * 1.4426950408889634f; // 1/sqrt(128)*log2e
    const float THR = 16.f;   // defer-max: P bounded by 2^(C1*16) ~= 4.1

    int wr_off[4], rd_off[2];
#pragma unroll
    for (int jc = 0; jc < 4; jc++)
        wr_off[jc] = (fr * 64 + jc * 16 + fq * 4) ^ ((fr & 7) << 3);
#pragma unroll
    for (int kc = 0; kc < 2; kc++)
        rd_off[kc] = (fr * 64 + kc * 32 + fq * 8) ^ ((fr & 7) << 3);
    int colKb[4], colVb[2];
#pragma unroll
    for (int c = 0; c < 4; c++) colKb[c] = (c * 64 + fq * 16) ^ ((fr & 7) << 4);
#pragma unroll
    for (int kc = 0; kc < 2; kc++) colVb[kc] = (kc * 64 + fq * 16) ^ ((fr & 7) << 4);

    auto stageK = [&](int kvt) {
        const int buf = kvt & 3;
        const char* Kg = (const char*)(Kh + (long)kvt * 64 * DK);
        char* Kd = (char*)lds + buf * 16384;
#pragma unroll
        for (int i = 0; i < 2; i++) {
            int a = (w * 2 + i) * 1024 + (lane << 4);
            int src = a ^ (((a >> 8) & 7) << 4);
            gld_lds16(Kg + src, Kd + (w * 2 + i) * 1024);
        }
    };
    auto stageV = [&](int kvt) {
        const int buf = kvt & 3;
        char* Vd = (char*)lds + 65536 + buf * 16384;
#pragma unroll
        for (int i = 0; i < 2; i++) {
            int a = (w * 2 + i) * 1024 + (lane << 4);
            int row = a >> 7;
            int inner = (a & 127) ^ ((row & 7) << 4);
            const char* src = (const char*)Vh + ((long)row * N_TOK + (long)kvt * 64) * 2 + inner;
            gld_lds16(src, Vd + (w * 2 + i) * 1024);
        }
    };

    const int NT = N_TOK / 64;   // 32
    stageK(0); stageV(0); stageK(1); stageV(1); stageK(2); stageV(2); stageK(3);
    asm volatile("s_waitcnt vmcnt(12)" ::: "memory");
    __builtin_amdgcn_s_barrier();
    __builtin_amdgcn_sched_barrier(0);

    for (int t = 0; t < NT; t++) {
        const char* Kcb = (const char*)lds + (t & 3) * 16384;
        f32x4 s[4] = {};
#pragma unroll
        for (int jc = 0; jc < 4; jc++) {
            const char* rb = Kcb + (jc * 16 + fr) * 256;
#pragma unroll
            for (int c = 0; c < 4; c++) {
                short8 kf = *(const short8*)(rb + colKb[c]);
                s[jc] = __builtin_amdgcn_mfma_f32_16x16x32_bf16(kf, qf[c], s[jc], 0, 0, 0);
            }
        }

        float tm = -1e30f;
#pragma unroll
        for (int jc = 0; jc < 4; jc++)
#pragma unroll
            for (int r = 0; r < 4; r++) tm = fmaxf(tm, s[jc][r]);
        tm = fmaxf(tm, __shfl_xor(tm, 16));
        tm = fmaxf(tm, __shfl_xor(tm, 32));
        // defer-max (T13): only rescale when the new tile max exceeds headroom
        if (!__all(tm <= mrow + THR)) {
            float nm = fmaxf(mrow, tm);
            float resc = exp2f(C1 * (mrow - nm));
            mrow = nm;
            lrow *= resc;
#pragma unroll
            for (int f = 0; f < 8; f++)
#pragma unroll
                for (int r = 0; r < 4; r++) oacc[f][r] *= resc;
        }
        float sum = 0.f;
#pragma unroll
        for (int jc = 0; jc < 4; jc++)
#pragma unroll
            for (int r = 0; r < 4; r++) {
                float p = exp2f(C1 * (s[jc][r] - mrow));
                s[jc][r] = p;
                sum += p;
            }
        sum += __shfl_xor(sum, 16);
        sum += __shfl_xor(sum, 32);
        lrow += sum;

#pragma unroll
        for (int jc = 0; jc < 4; jc++) {
            s16x4 pk;
            pk[0] = f2bf(s[jc][0]); pk[1] = f2bf(s[jc][1]);
            pk[2] = f2bf(s[jc][2]); pk[3] = f2bf(s[jc][3]);
            *(s16x4*)(Pw + wr_off[jc]) = pk;
        }
        short8 pa[2];
#pragma unroll
        for (int kc = 0; kc < 2; kc++)
            pa[kc] = *(const short8*)(Pw + rd_off[kc]);

        if (t < NT - 4) asm volatile("s_waitcnt vmcnt(8)" ::: "memory");
        else            asm volatile("s_waitcnt vmcnt(0)" ::: "memory");
        __builtin_amdgcn_sched_barrier(0);
        __builtin_amdgcn_s_barrier();
        __builtin_amdgcn_sched_barrier(0);

        const char* Vcb = (const char*)lds + 65536 + (t & 3) * 16384;
#pragma unroll
        for (int f = 0; f < 8; f++) {
            const char* rb = Vcb + (f * 16 + fr) * 128;
#pragma unroll
            for (int kc = 0; kc < 2; kc++) {
                short8 vf = *(const short8*)(rb + colVb[kc]);
                oacc[f] = __builtin_amdgcn_mfma_f32_16x16x32_bf16(vf, pa[kc], oacc[f], 0, 0, 0);
            }
        }

        if (t + 4 < NT) stageK(t + 4);
        if (t + 3 < NT) stageV(t + 3);
    }

    const float inv = 1.f / lrow;
    const long row = qbase + fr;
#pragma unroll
    for (int f = 0; f < 8; f++) {
        s16x4 ob;
        ob[0] = f2bf(oacc[f][0] * inv); ob[1] = f2bf(oacc[f][1] * inv);
        ob[2] = f2bf(oacc[f][2] * inv); ob[3] = f2bf(oacc[f][3] * inv);
        *(s16x4*)(O + row * (long)DMODEL + h * DK + f * 16 + fq * 4) = ob;
    }
}

// -------- fused Add + LayerNorm (B operand bf16), 1 block = 1 row -----------
__global__ __launch_bounds__(256) void add_ln1(const float* __restrict__ A,
                                               const short* __restrict__ B,
                                               const float* __restrict__ alpha,
                                               const float* __restrict__ beta,
                                               float* __restrict__ out,
                                               short* __restrict__ outbf) {
    const int row = blockIdx.x, t = threadIdx.x;
    const long base = (long)row * DMODEL;
    float x[8];
    float s = 0.f, q = 0.f;
#pragma unroll
    for (int i = 0; i < 2; i++) {
        long off = base + (long)(t + i * 256) * 4;
        float4 va = *(const float4*)(A + off);
        s16x4 vb = *(const s16x4*)(B + off);
        float xa[4] = { va.x, va.y, va.z, va.w };
#pragma unroll
        for (int j = 0; j < 4; j++) {
            float v = xa[j] + bf2f(vb[j]);
            x[i * 4 + j] = v;
            s += v; q += v * v;
        }
    }
#pragma unroll
    for (int o = 1; o < 64; o <<= 1) { s += __shfl_xor(s, o); q += __shfl_xor(q, o); }
    __shared__ float red[8];
    if ((t & 63) == 0) { red[t >> 6] = s; red[4 + (t >> 6)] = q; }
    __syncthreads();
    s = red[0] + red[1] + red[2] + red[3];
    q = red[4] + red[5] + red[6] + red[7];
    const float mean = s * (1.f / DMODEL);
    const float var = q * (1.f / DMODEL) - mean * mean;
    const float rstd = rsqrtf(var + 1e-5f);
#pragma unroll
    for (int i = 0; i < 2; i++) {
        long off = base + (long)(t + i * 256) * 4;
        float4 al = *(const float4*)(alpha + off);
        float4 be = *(const float4*)(beta + off);
        float a[4] = { al.x, al.y, al.z, al.w };
        float b[4] = { be.x, be.y, be.z, be.w };
#pragma unroll
        for (int j = 0; j < 4; j++) {
            float o2 = (x[i * 4 + j] - mean) * rstd * a[j] + b[j];
            out[off + j] = o2;
            outbf[off + j] = f2bf(o2);
        }
    }
}

// -------- Add + LN2 with 4-slab (bf16) split-K reduction + bias -------------
__global__ __launch_bounds__(256) void add_ln2_red(const float* __restrict__ H1,
                                                   const short* __restrict__ F4,
                                                   const float* __restrict__ b2,
                                                   const float* __restrict__ alpha,
                                                   const float* __restrict__ beta,
                                                   float* __restrict__ out) {
    const int row = blockIdx.x, t = threadIdx.x;
    const long base = (long)row * DMODEL;
    const long SL = (long)N_TOK * DMODEL;
    float x[8];
    float s = 0.f, q = 0.f;
#pragma unroll
    for (int i = 0; i < 2; i++) {
        long off = base + (long)(t + i * 256) * 4;
        int col = (t + i * 256) * 4;
        float4 a  = *(const float4*)(H1 + off);
        s16x4 f0 = *(const s16x4*)(F4 + off);
        s16x4 f1 = *(const s16x4*)(F4 + off + SL);
        s16x4 f2 = *(const s16x4*)(F4 + off + 2 * SL);
        s16x4 f3 = *(const s16x4*)(F4 + off + 3 * SL);
        float4 bb = *(const float4*)(b2 + col);
        float xa[4] = { a.x + bb.x, a.y + bb.y, a.z + bb.z, a.w + bb.w };
#pragma unroll
        for (int j = 0; j < 4; j++) {
            float v = xa[j] + bf2f(f0[j]) + bf2f(f1[j]) + bf2f(f2[j]) + bf2f(f3[j]);
            x[i * 4 + j] = v;
            s += v; q += v * v;
        }
    }
#pragma unroll
    for (int o = 1; o < 64; o <<= 1) { s += __shfl_xor(s, o); q += __shfl_xor(q, o); }
    __shared__ float red[8];
    if ((t & 63) == 0) { red[t >> 6] = s; red[4 + (t >> 6)] = q; }
    __syncthreads();
    s = red[0] + red[1] + red[2] + red[3];
    q = red[4] + red[5] + red[6] + red[7];
    const float mean = s * (1.f / DMODEL);
    const float var = q * (1.f / DMODEL) - mean * mean;
    const float rstd = rsqrtf(var + 1e-5f);
#pragma unroll
    for (int i = 0; i < 2; i++) {
        long off = base + (long)(t + i * 256) * 4;
        float4 al = *(const float4*)(alpha + off);
        float4 be = *(const float4*)(beta + off);
        float a[4] = { al.x, al.y, al.z, al.w };
        float b[4] = { be.x, be.y, be.z, be.w };
#pragma unroll
        for (int j = 0; j < 4; j++)
            out[off + j] = (x[i * 4 + j] - mean) * rstd * a[j] + b[j];
    }
}

extern "C" void kernel_launch(void* const* d_in, const int* in_sizes, int n_in,
                              void* d_out, int out_size, void* d_ws, size_t ws_size,
                              hipStream_t stream) {
    const float* X      = (const float*)d_in[0];
    const float* Wq     = (const float*)d_in[1];
    const float* bq     = (const float*)d_in[2];
    const float* Wk     = (const float*)d_in[3];
    const float* bk     = (const float*)d_in[4];
    const float* Wv     = (const float*)d_in[5];
    const float* bv     = (const float*)d_in[6];
    const float* alpha1 = (const float*)d_in[7];
    const float* beta1  = (const float*)d_in[8];
    const float* W1     = (const float*)d_in[9];
    const float* b1     = (const float*)d_in[10];
    const float* W2     = (const float*)d_in[11];
    const float* b2     = (const float*)d_in[12];
    const float* alpha2 = (const float*)d_in[13];
    const float* beta2  = (const float*)d_in[14];
    float* out = (float*)d_out;

    char* ws = (char*)d_ws;
    size_t off = 0;
    auto alloc = [&](size_t bytes) -> void* {
        void* p = ws + off;
        off += (bytes + 255) & ~(size_t)255;
        return p;
    };
    short* XBF   = (short*)alloc(2048UL * 2048 * 2);       // dead after QKV gemm
    short* WQKVT = (short*)alloc(48UL * 128 * 2048 * 2);   // dead after QKV
    short* W1T   = (short*)alloc(8192UL * 2048 * 2);       // dead after FFN1
    short* W2T   = (short*)alloc(2048UL * 8192 * 2);
    short* QKV   = (short*)alloc(48UL * 2048 * 128 * 2);   // Q(0-15),K(16-31),V(32-47)
    short* VT    = (short*)alloc(16UL * 128 * 2048 * 2);
    short* ATTN  = (short*)alloc(2048UL * 2048 * 2);       // bf16 now
    float* H1    = (float*)alloc(2048UL * 2048 * 4);
    short* H1BF  = (short*)alloc(2048UL * 2048 * 2);
    short* G     = (short*)alloc(2048UL * 8192 * 2);
    // F4 (32 MB, 4 bf16 split-K slabs) aliases XBF+WQKVT (dead by FFN2)
    short* F4 = XBF;

    // 1. casts / transposes
    cast_f32_bf16<<<2048, 256, 0, stream>>>(X, XBF, 2048 * 2048 / 8);
    transpose_cast<float><<<dim3(2, 32, 16), 256, 0, stream>>>(Wq, WQKVT,                    2048, 128, 2048L * 128, 128L * 2048);
    transpose_cast<float><<<dim3(2, 32, 16), 256, 0, stream>>>(Wk, WQKVT + 16L * 128 * 2048, 2048, 128, 2048L * 128, 128L * 2048);
    transpose_cast<float><<<dim3(2, 32, 16), 256, 0, stream>>>(Wv, WQKVT + 32L * 128 * 2048, 2048, 128, 2048L * 128, 128L * 2048);
    transpose_cast<float><<<dim3(128, 32, 1), 256, 0, stream>>>(W1, W1T, 2048, 8192, 0, 0);
    transpose_cast<float><<<dim3(32, 128, 1), 256, 0, stream>>>(W2, W2T, 8192, 2048, 0, 0);

    // 2. QKV fused GEMM: M=2048, N=6144 (TM=8, TN=24 -> 192 blocks)
    gemm256<0><<<192, 512, 0, stream>>>(XBF, WQKVT, QKV, bq, bk, bv, 2048, 8);

    // 3. V -> V^T per head
    transpose_cast<__hip_bfloat16><<<dim3(2, 32, 16), 256, 0, stream>>>(
        (const __hip_bfloat16*)(QKV + 32L * 2048 * 128), VT, 2048, 128, 2048L * 128, 128L * 2048);

    // 4. attention (256 blocks x 8 waves; 4-deep pipelined K/V, defer-max)
    attn_flash<<<256, 512, 0, stream>>>(QKV, QKV + 16L * 2048 * 128, VT, ATTN);

    // 5. Add & LN 1 (attn operand bf16)
    add_ln1<<<2048, 256, 0, stream>>>(X, ATTN, alpha1, beta1, H1, H1BF);

    // 6. FFN: FFN1 M=2048 N=8192 (256 blocks); FFN2 split-K=4 (256 blocks)
    gemm256<1><<<256, 512, 0, stream>>>(H1BF, W1T, G, b1, nullptr, nullptr, 2048, 8);
    gemm256<2><<<256, 512, 0, stream>>>(G, W2T, F4, nullptr, nullptr, nullptr, 8192, 8);

    // 7. Add + reduce + LN 2 -> output
    add_ln2_red<<<2048, 256, 0, stream>>>(H1, F4, b2, alpha2, beta2, out);
}

// Round 16
// 354.176 us; speedup vs baseline: 1.1368x; 1.0290x over previous
//
#include <hip/hip_runtime.h>
#include <hip/hip_bf16.h>

#define N_TOK 2048
#define DMODEL 2048
#define NH 16
#define DK 128
#define DFF 8192

typedef __attribute__((ext_vector_type(8))) short short8;
typedef __attribute__((ext_vector_type(4))) short s16x4;
typedef __attribute__((ext_vector_type(4))) float f32x4;

__device__ __forceinline__ short f2bf(float f) {
    unsigned int x = __builtin_bit_cast(unsigned int, f);
    unsigned int r = (x + 0x7fffu + ((x >> 16) & 1u)) >> 16;
    return (short)r;
}
__device__ __forceinline__ float bf2f(short s) {
    unsigned int u = ((unsigned int)(unsigned short)s) << 16;
    return __builtin_bit_cast(float, u);
}

// ---------------- cast X (f32 -> bf16), 8 elems/thread ----------------
__global__ __launch_bounds__(256) void cast_f32_bf16(const float* __restrict__ in,
                                                     short* __restrict__ out, int n8) {
    int i = blockIdx.x * 256 + threadIdx.x;
    if (i >= n8) return;
    const float4* p = (const float4*)in + (size_t)i * 2;
    float4 a = p[0], b = p[1];
    short8 o;
    o[0] = f2bf(a.x); o[1] = f2bf(a.y); o[2] = f2bf(a.z); o[3] = f2bf(a.w);
    o[4] = f2bf(b.x); o[5] = f2bf(b.y); o[6] = f2bf(b.z); o[7] = f2bf(b.w);
    *(short8*)(out + (size_t)i * 8) = o;
}

// --- transpose + cast to bf16 (64x64 LDS tiles, 16B reads + short8 writes) --
template <typename TIN>
__global__ __launch_bounds__(256) void transpose_cast(const TIN* __restrict__ in,
                                                      short* __restrict__ out,
                                                      int R, int C, long sIn, long sOut) {
    __shared__ float t[64][65];
    in  += (long)blockIdx.z * sIn;
    out += (long)blockIdx.z * sOut;
    const int tid = threadIdx.x;
    long r0 = (long)blockIdx.y * 64, c0 = (long)blockIdx.x * 64;
    if constexpr (sizeof(TIN) == 4) {
#pragma unroll
        for (int i = 0; i < 4; i++) {
            int r = (tid >> 4) + i * 16;
            int c = (tid & 15) * 4;
            float4 v = *(const float4*)((const float*)in + (r0 + r) * (long)C + c0 + c);
            t[r][c + 0] = v.x; t[r][c + 1] = v.y; t[r][c + 2] = v.z; t[r][c + 3] = v.w;
        }
    } else {
#pragma unroll
        for (int i = 0; i < 2; i++) {
            int r = (tid >> 3) + i * 32;
            int c = (tid & 7) * 8;
            short8 v = *(const short8*)((const short*)in + (r0 + r) * (long)C + c0 + c);
#pragma unroll
            for (int j = 0; j < 8; j++) t[r][c + j] = bf2f(v[j]);
        }
    }
    __syncthreads();
#pragma unroll
    for (int p = 0; p < 2; p++) {
        int c = (tid >> 3) + p * 32;
        int r8 = (tid & 7) * 8;
        short8 v;
#pragma unroll
        for (int j = 0; j < 8; j++) v[j] = f2bf(t[r8 + j][c]);
        *(short8*)(out + (c0 + c) * (long)R + r0 + r8) = v;
    }
}

// ---------------- async global->LDS helper ----------------
__device__ __forceinline__ void gld_lds16(const void* g, void* l) {
    __builtin_amdgcn_global_load_lds(
        (const __attribute__((address_space(1))) void*)g,
        (__attribute__((address_space(3))) void*)l, 16, 0, 0);
}

// ======== 256x256 bf16 GEMM, BK=64, 8 waves, 8-phase, B-read-once ===========
// (R13 configuration — best measured; plateaued ~850 TF at this shape)
#define VM8 asm volatile("s_waitcnt vmcnt(8)" ::: "memory")
#define VM0 asm volatile("s_waitcnt vmcnt(0)" ::: "memory")
#define VMNONE ((void)0)

#define PHASE(BUF, MH, NHI, RA, RBNH, STAGE_STMT, VMSTMT)                       \
  {                                                                             \
    if (RA) {                                                                   \
      _Pragma("unroll") for (int mp = 0; mp < 4; mp++)                          \
        _Pragma("unroll") for (int kk = 0; kk < 2; kk++) {                      \
          int rowA = wr * 128 + (MH) * 64 + mp * 16 + fr;                       \
          af[mp][kk] = *(const short8*)((const char*)lds + (BUF) * 65536 +      \
                         rowA * 128 + (((kk * 4 + fq) ^ (rowA & 7)) << 4));     \
        }                                                                       \
    }                                                                           \
    if ((RBNH) < 2) {                                                           \
      _Pragma("unroll") for (int np = 0; np < 2; np++)                          \
        _Pragma("unroll") for (int kk = 0; kk < 2; kk++) {                      \
          int rowB = wc * 64 + (RBNH) * 32 + np * 16 + fr;                      \
          bf[(RBNH) & 1][np][kk] =                                              \
              *(const short8*)((const char*)lds + (BUF) * 65536 + 32768 +       \
                  rowB * 128 + (((kk * 4 + fq) ^ (rowB & 7)) << 4));            \
        }                                                                       \
    }                                                                           \
    STAGE_STMT;                                                                 \
    __builtin_amdgcn_s_barrier();                                               \
    __builtin_amdgcn_s_setprio(1);                                              \
    _Pragma("unroll") for (int mp = 0; mp < 4; mp++)                            \
      _Pragma("unroll") for (int np = 0; np < 2; np++)                          \
        _Pragma("unroll") for (int kk = 0; kk < 2; kk++)                        \
          acc[(MH) * 4 + mp][(NHI) * 2 + np] =                                  \
              __builtin_amdgcn_mfma_f32_16x16x32_bf16(                          \
                  af[mp][kk], bf[NHI][np][kk], acc[(MH) * 4 + mp][(NHI) * 2 + np],\
                  0, 0, 0);                                                     \
    __builtin_amdgcn_s_setprio(0);                                              \
    VMSTMT;                                                                     \
    __builtin_amdgcn_s_barrier();                                               \
  }

template <int MODE>
__global__ __launch_bounds__(512, 2) void gemm256(const short* __restrict__ A,
                                                  const short* __restrict__ Bt,
                                                  void* __restrict__ Cv,
                                                  const float* __restrict__ b0,
                                                  const float* __restrict__ b1,
                                                  const float* __restrict__ b2,
                                                  int Ktot, int TM) {
    __shared__ short lds[65536];   // 128 KB
    const int tid = threadIdx.x, lane = tid & 63, w = tid >> 6;
    const int T = gridDim.x, bid = blockIdx.x;
    const int vbid = (bid & 7) * (T >> 3) + (bid >> 3);   // XCD chunking
    const int mt = vbid % TM;
    const int rest = vbid / TM;
    int nt = rest, z = 0;
    if (MODE == 2) { nt = rest & 7; z = rest >> 3; }
    const long brow = (long)mt * 256, bcol = (long)nt * 256;
    const short* Ab = A + (MODE == 2 ? (long)z * 2048 : 0);
    const short* Bb = Bt + (MODE == 2 ? (long)z * 2048 : 0);

    auto stageA = [&](int kt, int buf, int mh) {
#pragma unroll
        for (int j = 0; j < 2; j++) {
            int row = mh * 64 + j * 128 + (tid >> 3);
            int g = (lane & 7) ^ (row & 7);
            gld_lds16((const char*)(Ab + (brow + row) * (long)Ktot + (long)kt * 64) + g * 16,
                      (char*)lds + buf * 65536 + mh * 8192 + j * 16384 + w * 1024 + lane * 16);
        }
    };
    auto stageB = [&](int kt, int buf, int nh) {
#pragma unroll
        for (int j = 0; j < 2; j++) {
            int s = 2 * j + (w >> 2);
            int rin = (w & 3) * 8 + (lane >> 3);
            int row = s * 64 + nh * 32 + rin;
            int g = (lane & 7) ^ (row & 7);
            gld_lds16((const char*)(Bb + (bcol + row) * (long)Ktot + (long)kt * 64) + g * 16,
                      (char*)lds + buf * 65536 + 32768 + j * 16384 + (w >> 2) * 8192 +
                          nh * 4096 + (w & 3) * 1024 + lane * 16);
        }
    };

    const int wr = w >> 2, wc = w & 3;          // 2 x 4 wave grid (128 x 64 out)
    const int fr = lane & 15, fq = lane >> 4;
    f32x4 acc[8][4] = {};
    short8 af[4][2], bf[2][2][2];

    stageA(0, 0, 0); stageB(0, 0, 0); stageB(0, 0, 1); stageA(0, 0, 1);
    stageA(1, 1, 0); stageB(1, 1, 0); stageB(1, 1, 1); stageA(1, 1, 1);
    VM8;
    __builtin_amdgcn_s_barrier();

    for (int i = 0; i < 15; i++) {
        const int kn = 2 * i + 2;
        PHASE(0, 0, 0, 1, 0, {}, VMNONE)
        PHASE(0, 0, 1, 0, 1, { stageA(kn, 0, 0); stageB(kn, 0, 0); }, VMNONE)
        PHASE(0, 1, 0, 1, 2, { stageB(kn, 0, 1); }, VMNONE)
        PHASE(0, 1, 1, 0, 2, { stageA(kn, 0, 1); }, VM8)
        PHASE(1, 0, 0, 1, 0, {}, VMNONE)
        PHASE(1, 0, 1, 0, 1, { stageA(kn + 1, 1, 0); stageB(kn + 1, 1, 0); }, VMNONE)
        PHASE(1, 1, 0, 1, 2, { stageB(kn + 1, 1, 1); }, VMNONE)
        PHASE(1, 1, 1, 0, 2, { stageA(kn + 1, 1, 1); }, VM8)
    }
    PHASE(0, 0, 0, 1, 0, {}, VMNONE)
    PHASE(0, 0, 1, 0, 1, {}, VMNONE)
    PHASE(0, 1, 0, 1, 2, {}, VMNONE)
    PHASE(0, 1, 1, 0, 2, {}, VM0)
    PHASE(1, 0, 0, 1, 0, {}, VMNONE)
    PHASE(1, 0, 1, 0, 1, {}, VMNONE)
    PHASE(1, 1, 0, 1, 2, {}, VMNONE)
    PHASE(1, 1, 1, 0, 2, {}, VMNONE)

    const long crow0 = brow + wr * 128, ccol0 = bcol + wc * 64;
#pragma unroll
    for (int n = 0; n < 4; n++) {
        const long col = ccol0 + (n >> 1) * 32 + (n & 1) * 16 + fr;
        float bval = 0.f;
        if (MODE == 0) {
            const float* bp = (col >> 11) == 0 ? b0 : (col >> 11) == 1 ? b1 : b2;
            bval = bp[col & 2047];
        } else if (MODE == 1) bval = b0[col];
#pragma unroll
        for (int m = 0; m < 8; m++) {
#pragma unroll
            for (int r = 0; r < 4; r++) {
                const long row = crow0 + (m >> 2) * 64 + (m & 3) * 16 + fq * 4 + r;
                float v = acc[m][n][r] + bval;
                if (MODE == 0) {
                    const long slab = col >> 7;
                    ((short*)Cv)[slab * (2048L * 128) + row * 128 + (col & 127)] = f2bf(v);
                } else if (MODE == 1) {
                    ((short*)Cv)[row * 8192 + col] = f2bf(fmaxf(v, 0.f));
                } else {
                    ((short*)Cv)[(long)z * (2048L * 2048) + row * 2048 + col] = f2bf(v);
                }
            }
        }
    }
}

// --- flash attention v8: 2-deep rings (80KB LDS -> 2 blocks/CU) + defer-max -
// LDS: K[2][16KB] | V[2][16KB] | P[8][2KB] = 80KB exactly -> 2 blocks/CU.
// vmcnt trace (loads, 2/stage): prologue K0,V0,K1 -> vmcnt(4) (K0 in).
// iter t: [t>0: vmcnt(t==NT-1?2:4) -> K(t)] QK; softmax; P;
//         vmcnt(t==NT-1?0:2) -> V(t); BARRIER; PV; issue V(t+1),K(t+2).
// Hazards: stage-writes post-barrier(t), last reads pre-barrier(t). Traced.
__global__ __launch_bounds__(512, 4) void attn_flash(const short* __restrict__ Q,
                                                     const short* __restrict__ Kc,
                                                     const short* __restrict__ VT,
                                                     short* __restrict__ O) {
    __shared__ short lds[40960];   // 80 KB
    const int tid = threadIdx.x, lane = tid & 63, w = tid >> 6;
    const int bid = blockIdx.x;
    const int vid = (bid & 7) * 32 + (bid >> 3);   // XCD-chunked swizzle
    const int h = vid >> 4, qt = vid & 15;
    const int fr = lane & 15, fq = lane >> 4;
    const long qbase = (long)qt * 128 + w * 16;
    const short* Qh = Q  + (long)h * N_TOK * DK;
    const short* Kh = Kc + (long)h * N_TOK * DK;
    const short* Vh = VT + (long)h * DK * N_TOK;
    short* Pw = lds + 32768 + w * 1024;

    short8 qf[4];
#pragma unroll
    for (int c = 0; c < 4; c++)
        qf[c] = *(const short8*)(Qh + (qbase + fr) * DK + c * 32 + fq * 8);

    float mrow = -1e30f, lrow = 0.f;
    f32x4 oacc[8] = {};
    const float C1 = 0.08838834764831845f * 1.4426950408889634f; // 1/sqrt(128)*log2e
    const float THR = 16.f;

    int wr_off[4], rd_off[2];
#pragma unroll
    for (int jc = 0; jc < 4; jc++)
        wr_off[jc] = (fr * 64 + jc * 16 + fq * 4) ^ ((fr & 7) << 3);
#pragma unroll
    for (int kc = 0; kc < 2; kc++)
        rd_off[kc] = (fr * 64 + kc * 32 + fq * 8) ^ ((fr & 7) << 3);
    int colKb[4], colVb[2];
#pragma unroll
    for (int c = 0; c < 4; c++) colKb[c] = (c * 64 + fq * 16) ^ ((fr & 7) << 4);
#pragma unroll
    for (int kc = 0; kc < 2; kc++) colVb[kc] = (kc * 64 + fq * 16) ^ ((fr & 7) << 4);

    auto stageK = [&](int kvt) {
        const int buf = kvt & 1;
        const char* Kg = (const char*)(Kh + (long)kvt * 64 * DK);
        char* Kd = (char*)lds + buf * 16384;
#pragma unroll
        for (int i = 0; i < 2; i++) {
            int a = (w * 2 + i) * 1024 + (lane << 4);
            int src = a ^ (((a >> 8) & 7) << 4);
            gld_lds16(Kg + src, Kd + (w * 2 + i) * 1024);
        }
    };
    auto stageV = [&](int kvt) {
        const int buf = kvt & 1;
        char* Vd = (char*)lds + 32768 + buf * 16384;
#pragma unroll
        for (int i = 0; i < 2; i++) {
            int a = (w * 2 + i) * 1024 + (lane << 4);
            int row = a >> 7;
            int inner = (a & 127) ^ ((row & 7) << 4);
            const char* src = (const char*)Vh + ((long)row * N_TOK + (long)kvt * 64) * 2 + inner;
            gld_lds16(src, Vd + (w * 2 + i) * 1024);
        }
    };

    const int NT = N_TOK / 64;   // 32
    stageK(0); stageV(0); stageK(1);
    asm volatile("s_waitcnt vmcnt(4)" ::: "memory");
    __builtin_amdgcn_s_barrier();
    __builtin_amdgcn_sched_barrier(0);

    for (int t = 0; t < NT; t++) {
        if (t > 0) {
            if (t == NT - 1) asm volatile("s_waitcnt vmcnt(2)" ::: "memory");
            else             asm volatile("s_waitcnt vmcnt(4)" ::: "memory");
            __builtin_amdgcn_sched_barrier(0);
        }
        const char* Kcb = (const char*)lds + (t & 1) * 16384;
        f32x4 s[4] = {};
#pragma unroll
        for (int jc = 0; jc < 4; jc++) {
            const char* rb = Kcb + (jc * 16 + fr) * 256;
#pragma unroll
            for (int c = 0; c < 4; c++) {
                short8 kf = *(const short8*)(rb + colKb[c]);
                s[jc] = __builtin_amdgcn_mfma_f32_16x16x32_bf16(kf, qf[c], s[jc], 0, 0, 0);
            }
        }

        float tm = -1e30f;
#pragma unroll
        for (int jc = 0; jc < 4; jc++)
#pragma unroll
            for (int r = 0; r < 4; r++) tm = fmaxf(tm, s[jc][r]);
        tm = fmaxf(tm, __shfl_xor(tm, 16));
        tm = fmaxf(tm, __shfl_xor(tm, 32));
        if (!__all(tm <= mrow + THR)) {
            float nm = fmaxf(mrow, tm);
            float resc = exp2f(C1 * (mrow - nm));
            mrow = nm;
            lrow *= resc;
#pragma unroll
            for (int f = 0; f < 8; f++)
#pragma unroll
                for (int r = 0; r < 4; r++) oacc[f][r] *= resc;
        }
        float sum = 0.f;
#pragma unroll
        for (int jc = 0; jc < 4; jc++)
#pragma unroll
            for (int r = 0; r < 4; r++) {
                float p = exp2f(C1 * (s[jc][r] - mrow));
                s[jc][r] = p;
                sum += p;
            }
        sum += __shfl_xor(sum, 16);
        sum += __shfl_xor(sum, 32);
        lrow += sum;

#pragma unroll
        for (int jc = 0; jc < 4; jc++) {
            s16x4 pk;
            pk[0] = f2bf(s[jc][0]); pk[1] = f2bf(s[jc][1]);
            pk[2] = f2bf(s[jc][2]); pk[3] = f2bf(s[jc][3]);
            *(s16x4*)(Pw + wr_off[jc]) = pk;
        }
        short8 pa[2];
#pragma unroll
        for (int kc = 0; kc < 2; kc++)
            pa[kc] = *(const short8*)(Pw + rd_off[kc]);

        if (t == NT - 1) asm volatile("s_waitcnt vmcnt(0)" ::: "memory");
        else             asm volatile("s_waitcnt vmcnt(2)" ::: "memory");
        __builtin_amdgcn_sched_barrier(0);
        __builtin_amdgcn_s_barrier();
        __builtin_amdgcn_sched_barrier(0);

        const char* Vcb = (const char*)lds + 32768 + (t & 1) * 16384;
#pragma unroll
        for (int f = 0; f < 8; f++) {
            const char* rb = Vcb + (f * 16 + fr) * 128;
#pragma unroll
            for (int kc = 0; kc < 2; kc++) {
                short8 vf = *(const short8*)(rb + colVb[kc]);
                oacc[f] = __builtin_amdgcn_mfma_f32_16x16x32_bf16(vf, pa[kc], oacc[f], 0, 0, 0);
            }
        }

        if (t + 1 < NT) stageV(t + 1);
        if (t + 2 < NT) stageK(t + 2);
    }

    const float inv = 1.f / lrow;
    const long row = qbase + fr;
#pragma unroll
    for (int f = 0; f < 8; f++) {
        s16x4 ob;
        ob[0] = f2bf(oacc[f][0] * inv); ob[1] = f2bf(oacc[f][1] * inv);
        ob[2] = f2bf(oacc[f][2] * inv); ob[3] = f2bf(oacc[f][3] * inv);
        *(s16x4*)(O + row * (long)DMODEL + h * DK + f * 16 + fq * 4) = ob;
    }
}

// -------- fused Add + LayerNorm (B bf16), writes bf16 only ------------------
__global__ __launch_bounds__(256) void add_ln1(const float* __restrict__ A,
                                               const short* __restrict__ B,
                                               const float* __restrict__ alpha,
                                               const float* __restrict__ beta,
                                               short* __restrict__ outbf) {
    const int row = blockIdx.x, t = threadIdx.x;
    const long base = (long)row * DMODEL;
    float x[8];
    float s = 0.f, q = 0.f;
#pragma unroll
    for (int i = 0; i < 2; i++) {
        long off = base + (long)(t + i * 256) * 4;
        float4 va = *(const float4*)(A + off);
        s16x4 vb = *(const s16x4*)(B + off);
        float xa[4] = { va.x, va.y, va.z, va.w };
#pragma unroll
        for (int j = 0; j < 4; j++) {
            float v = xa[j] + bf2f(vb[j]);
            x[i * 4 + j] = v;
            s += v; q += v * v;
        }
    }
#pragma unroll
    for (int o = 1; o < 64; o <<= 1) { s += __shfl_xor(s, o); q += __shfl_xor(q, o); }
    __shared__ float red[8];
    if ((t & 63) == 0) { red[t >> 6] = s; red[4 + (t >> 6)] = q; }
    __syncthreads();
    s = red[0] + red[1] + red[2] + red[3];
    q = red[4] + red[5] + red[6] + red[7];
    const float mean = s * (1.f / DMODEL);
    const float var = q * (1.f / DMODEL) - mean * mean;
    const float rstd = rsqrtf(var + 1e-5f);
#pragma unroll
    for (int i = 0; i < 2; i++) {
        long off = base + (long)(t + i * 256) * 4;
        float4 al = *(const float4*)(alpha + off);
        float4 be = *(const float4*)(beta + off);
        float a[4] = { al.x, al.y, al.z, al.w };
        float b[4] = { be.x, be.y, be.z, be.w };
        s16x4 ob;
#pragma unroll
        for (int j = 0; j < 4; j++)
            ob[j] = f2bf((x[i * 4 + j] - mean) * rstd * a[j] + b[j]);
        *(s16x4*)(outbf + off) = ob;
    }
}

// ---- Add + LN2: h1 (bf16) + 4 bf16 split-K slabs + bias -> f32 out ---------
__global__ __launch_bounds__(256) void add_ln2_red(const short* __restrict__ H1,
                                                   const short* __restrict__ F4,
                                                   const float* __restrict__ b2,
                                                   const float* __restrict__ alpha,
                                                   const float* __restrict__ beta,
                                                   float* __restrict__ out) {
    const int row = blockIdx.x, t = threadIdx.x;
    const long base = (long)row * DMODEL;
    const long SL = (long)N_TOK * DMODEL;
    float x[8];
    float s = 0.f, q = 0.f;
#pragma unroll
    for (int i = 0; i < 2; i++) {
        long off = base + (long)(t + i * 256) * 4;
        int col = (t + i * 256) * 4;
        s16x4 a  = *(const s16x4*)(H1 + off);
        s16x4 f0 = *(const s16x4*)(F4 + off);
        s16x4 f1 = *(const s16x4*)(F4 + off + SL);
        s16x4 f2 = *(const s16x4*)(F4 + off + 2 * SL);
        s16x4 f3 = *(const s16x4*)(F4 + off + 3 * SL);
        float4 bb = *(const float4*)(b2 + col);
        float ba[4] = { bb.x, bb.y, bb.z, bb.w };
#pragma unroll
        for (int j = 0; j < 4; j++) {
            float v = bf2f(a[j]) + ba[j] + bf2f(f0[j]) + bf2f(f1[j]) + bf2f(f2[j]) + bf2f(f3[j]);
            x[i * 4 + j] = v;
            s += v; q += v * v;
        }
    }
#pragma unroll
    for (int o = 1; o < 64; o <<= 1) { s += __shfl_xor(s, o); q += __shfl_xor(q, o); }
    __shared__ float red[8];
    if ((t & 63) == 0) { red[t >> 6] = s; red[4 + (t >> 6)] = q; }
    __syncthreads();
    s = red[0] + red[1] + red[2] + red[3];
    q = red[4] + red[5] + red[6] + red[7];
    const float mean = s * (1.f / DMODEL);
    const float var = q * (1.f / DMODEL) - mean * mean;
    const float rstd = rsqrtf(var + 1e-5f);
#pragma unroll
    for (int i = 0; i < 2; i++) {
        long off = base + (long)(t + i * 256) * 4;
        float4 al = *(const float4*)(alpha + off);
        float4 be = *(const float4*)(beta + off);
        float a[4] = { al.x, al.y, al.z, al.w };
        float b[4] = { be.x, be.y, be.z, be.w };
#pragma unroll
        for (int j = 0; j < 4; j++)
            out[off + j] = (x[i * 4 + j] - mean) * rstd * a[j] + b[j];
    }
}

extern "C" void kernel_launch(void* const* d_in, const int* in_sizes, int n_in,
                              void* d_out, int out_size, void* d_ws, size_t ws_size,
                              hipStream_t stream) {
    const float* X      = (const float*)d_in[0];
    const float* Wq     = (const float*)d_in[1];
    const float* bq     = (const float*)d_in[2];
    const float* Wk     = (const float*)d_in[3];
    const float* bk     = (const float*)d_in[4];
    const float* Wv     = (const float*)d_in[5];
    const float* bv     = (const float*)d_in[6];
    const float* alpha1 = (const float*)d_in[7];
    const float* beta1  = (const float*)d_in[8];
    const float* W1     = (const float*)d_in[9];
    const float* b1     = (const float*)d_in[10];
    const float* W2     = (const float*)d_in[11];
    const float* b2     = (const float*)d_in[12];
    const float* alpha2 = (const float*)d_in[13];
    const float* beta2  = (const float*)d_in[14];
    float* out = (float*)d_out;

    char* ws = (char*)d_ws;
    size_t off = 0;
    auto alloc = [&](size_t bytes) -> void* {
        void* p = ws + off;
        off += (bytes + 255) & ~(size_t)255;
        return p;
    };
    short* XBF   = (short*)alloc(2048UL * 2048 * 2);       // dead after QKV gemm
    short* WQKVT = (short*)alloc(48UL * 128 * 2048 * 2);   // dead after QKV
    short* W1T   = (short*)alloc(8192UL * 2048 * 2);       // dead after FFN1
    short* W2T   = (short*)alloc(2048UL * 8192 * 2);
    short* QKV   = (short*)alloc(48UL * 2048 * 128 * 2);   // Q(0-15),K(16-31),V(32-47)
    short* VT    = (short*)alloc(16UL * 128 * 2048 * 2);
    short* ATTN  = (short*)alloc(2048UL * 2048 * 2);       // bf16
    short* H1BF  = (short*)alloc(2048UL * 2048 * 2);
    short* G     = (short*)alloc(2048UL * 8192 * 2);
    // F4 (32 MB, 4 bf16 split-K slabs) aliases XBF+WQKVT (dead by FFN2)
    short* F4 = XBF;

    // 1. casts / transposes
    cast_f32_bf16<<<2048, 256, 0, stream>>>(X, XBF, 2048 * 2048 / 8);
    transpose_cast<float><<<dim3(2, 32, 16), 256, 0, stream>>>(Wq, WQKVT,                    2048, 128, 2048L * 128, 128L * 2048);
    transpose_cast<float><<<dim3(2, 32, 16), 256, 0, stream>>>(Wk, WQKVT + 16L * 128 * 2048, 2048, 128, 2048L * 128, 128L * 2048);
    transpose_cast<float><<<dim3(2, 32, 16), 256, 0, stream>>>(Wv, WQKVT + 32L * 128 * 2048, 2048, 128, 2048L * 128, 128L * 2048);
    transpose_cast<float><<<dim3(128, 32, 1), 256, 0, stream>>>(W1, W1T, 2048, 8192, 0, 0);
    transpose_cast<float><<<dim3(32, 128, 1), 256, 0, stream>>>(W2, W2T, 8192, 2048, 0, 0);

    // 2. QKV fused GEMM: M=2048, N=6144 (TM=8, TN=24 -> 192 blocks)
    gemm256<0><<<192, 512, 0, stream>>>(XBF, WQKVT, QKV, bq, bk, bv, 2048, 8);

    // 3. V -> V^T per head
    transpose_cast<__hip_bfloat16><<<dim3(2, 32, 16), 256, 0, stream>>>(
        (const __hip_bfloat16*)(QKV + 32L * 2048 * 128), VT, 2048, 128, 2048L * 128, 128L * 2048);

    // 4. attention (256 blocks x 8 waves; 2-deep rings, 2 blocks/CU)
    attn_flash<<<256, 512, 0, stream>>>(QKV, QKV + 16L * 2048 * 128, VT, ATTN);

    // 5. Add & LN 1 (bf16 in/out)
    add_ln1<<<2048, 256, 0, stream>>>(X, ATTN, alpha1, beta1, H1BF);

    // 6. FFN: FFN1 M=2048 N=8192 (256 blocks); FFN2 split-K=4 (256 blocks)
    gemm256<1><<<256, 512, 0, stream>>>(H1BF, W1T, G, b1, nullptr, nullptr, 2048, 8);
    gemm256<2><<<256, 512, 0, stream>>>(G, W2T, F4, nullptr, nullptr, nullptr, 8192, 8);

    // 7. Add + reduce + LN 2 -> output
    add_ln2_red<<<2048, 256, 0, stream>>>(H1BF, F4, b2, alpha2, beta2, out);
}

// Round 17
// 334.641 us; speedup vs baseline: 1.2032x; 1.0584x over previous
//
#include <hip/hip_runtime.h>
#include <hip/hip_bf16.h>

#define N_TOK 2048
#define DMODEL 2048
#define NH 16
#define DK 128
#define DFF 8192

typedef __attribute__((ext_vector_type(8))) short short8;
typedef __attribute__((ext_vector_type(4))) short s16x4;
typedef __attribute__((ext_vector_type(4))) float f32x4;

__device__ __forceinline__ short f2bf(float f) {
    unsigned int x = __builtin_bit_cast(unsigned int, f);
    unsigned int r = (x + 0x7fffu + ((x >> 16) & 1u)) >> 16;
    return (short)r;
}
__device__ __forceinline__ float bf2f(short s) {
    unsigned int u = ((unsigned int)(unsigned short)s) << 16;
    return __builtin_bit_cast(float, u);
}

// ---------------- cast X (f32 -> bf16), 8 elems/thread ----------------
__global__ __launch_bounds__(256) void cast_f32_bf16(const float* __restrict__ in,
                                                     short* __restrict__ out, int n8) {
    int i = blockIdx.x * 256 + threadIdx.x;
    if (i >= n8) return;
    const float4* p = (const float4*)in + (size_t)i * 2;
    float4 a = p[0], b = p[1];
    short8 o;
    o[0] = f2bf(a.x); o[1] = f2bf(a.y); o[2] = f2bf(a.z); o[3] = f2bf(a.w);
    o[4] = f2bf(b.x); o[5] = f2bf(b.y); o[6] = f2bf(b.z); o[7] = f2bf(b.w);
    *(short8*)(out + (size_t)i * 8) = o;
}

// --- transpose + cast to bf16 (64x64 LDS tiles, 16B reads + short8 writes) --
template <typename TIN>
__global__ __launch_bounds__(256) void transpose_cast(const TIN* __restrict__ in,
                                                      short* __restrict__ out,
                                                      int R, int C, long sIn, long sOut) {
    __shared__ float t[64][65];
    in  += (long)blockIdx.z * sIn;
    out += (long)blockIdx.z * sOut;
    const int tid = threadIdx.x;
    long r0 = (long)blockIdx.y * 64, c0 = (long)blockIdx.x * 64;
    if constexpr (sizeof(TIN) == 4) {
#pragma unroll
        for (int i = 0; i < 4; i++) {
            int r = (tid >> 4) + i * 16;
            int c = (tid & 15) * 4;
            float4 v = *(const float4*)((const float*)in + (r0 + r) * (long)C + c0 + c);
            t[r][c + 0] = v.x; t[r][c + 1] = v.y; t[r][c + 2] = v.z; t[r][c + 3] = v.w;
        }
    } else {
#pragma unroll
        for (int i = 0; i < 2; i++) {
            int r = (tid >> 3) + i * 32;
            int c = (tid & 7) * 8;
            short8 v = *(const short8*)((const short*)in + (r0 + r) * (long)C + c0 + c);
#pragma unroll
            for (int j = 0; j < 8; j++) t[r][c + j] = bf2f(v[j]);
        }
    }
    __syncthreads();
#pragma unroll
    for (int p = 0; p < 2; p++) {
        int c = (tid >> 3) + p * 32;
        int r8 = (tid & 7) * 8;
        short8 v;
#pragma unroll
        for (int j = 0; j < 8; j++) v[j] = f2bf(t[r8 + j][c]);
        *(short8*)(out + (c0 + c) * (long)R + r0 + r8) = v;
    }
}

// ---------------- async global->LDS helper ----------------
__device__ __forceinline__ void gld_lds16(const void* g, void* l) {
    __builtin_amdgcn_global_load_lds(
        (const __attribute__((address_space(1))) void*)g,
        (__attribute__((address_space(3))) void*)l, 16, 0, 0);
}

// ======== 256x256 bf16 GEMM, BK=64, 8 waves, 8-phase, B-read-once ===========
// R16: epilogue LDS-bounced -> coalesced short8 C-stores (WRITE_SIZE 2.4x fix)
#define VM8 asm volatile("s_waitcnt vmcnt(8)" ::: "memory")
#define VM0 asm volatile("s_waitcnt vmcnt(0)" ::: "memory")
#define VMNONE ((void)0)

#define PHASE(BUF, MH, NHI, RA, RBNH, STAGE_STMT, VMSTMT)                       \
  {                                                                             \
    if (RA) {                                                                   \
      _Pragma("unroll") for (int mp = 0; mp < 4; mp++)                          \
        _Pragma("unroll") for (int kk = 0; kk < 2; kk++) {                      \
          int rowA = wr * 128 + (MH) * 64 + mp * 16 + fr;                       \
          af[mp][kk] = *(const short8*)((const char*)lds + (BUF) * 65536 +      \
                         rowA * 128 + (((kk * 4 + fq) ^ (rowA & 7)) << 4));     \
        }                                                                       \
    }                                                                           \
    if ((RBNH) < 2) {                                                           \
      _Pragma("unroll") for (int np = 0; np < 2; np++)                          \
        _Pragma("unroll") for (int kk = 0; kk < 2; kk++) {                      \
          int rowB = wc * 64 + (RBNH) * 32 + np * 16 + fr;                      \
          bf[(RBNH) & 1][np][kk] =                                              \
              *(const short8*)((const char*)lds + (BUF) * 65536 + 32768 +       \
                  rowB * 128 + (((kk * 4 + fq) ^ (rowB & 7)) << 4));            \
        }                                                                       \
    }                                                                           \
    STAGE_STMT;                                                                 \
    __builtin_amdgcn_s_barrier();                                               \
    __builtin_amdgcn_s_setprio(1);                                              \
    _Pragma("unroll") for (int mp = 0; mp < 4; mp++)                            \
      _Pragma("unroll") for (int np = 0; np < 2; np++)                          \
        _Pragma("unroll") for (int kk = 0; kk < 2; kk++)                        \
          acc[(MH) * 4 + mp][(NHI) * 2 + np] =                                  \
              __builtin_amdgcn_mfma_f32_16x16x32_bf16(                          \
                  af[mp][kk], bf[NHI][np][kk], acc[(MH) * 4 + mp][(NHI) * 2 + np],\
                  0, 0, 0);                                                     \
    __builtin_amdgcn_s_setprio(0);                                              \
    VMSTMT;                                                                     \
    __builtin_amdgcn_s_barrier();                                               \
  }

template <int MODE>
__global__ __launch_bounds__(512, 2) void gemm256(const short* __restrict__ A,
                                                  const short* __restrict__ Bt,
                                                  void* __restrict__ Cv,
                                                  const float* __restrict__ b0,
                                                  const float* __restrict__ b1,
                                                  const float* __restrict__ b2,
                                                  int Ktot, int TM) {
    __shared__ short lds[65536];   // 128 KB
    const int tid = threadIdx.x, lane = tid & 63, w = tid >> 6;
    const int T = gridDim.x, bid = blockIdx.x;
    const int vbid = (bid & 7) * (T >> 3) + (bid >> 3);   // XCD chunking
    const int mt = vbid % TM;
    const int rest = vbid / TM;
    int nt = rest, z = 0;
    if (MODE == 2) { nt = rest & 7; z = rest >> 3; }
    const long brow = (long)mt * 256, bcol = (long)nt * 256;
    const short* Ab = A + (MODE == 2 ? (long)z * 2048 : 0);
    const short* Bb = Bt + (MODE == 2 ? (long)z * 2048 : 0);

    auto stageA = [&](int kt, int buf, int mh) {
#pragma unroll
        for (int j = 0; j < 2; j++) {
            int row = mh * 64 + j * 128 + (tid >> 3);
            int g = (lane & 7) ^ (row & 7);
            gld_lds16((const char*)(Ab + (brow + row) * (long)Ktot + (long)kt * 64) + g * 16,
                      (char*)lds + buf * 65536 + mh * 8192 + j * 16384 + w * 1024 + lane * 16);
        }
    };
    auto stageB = [&](int kt, int buf, int nh) {
#pragma unroll
        for (int j = 0; j < 2; j++) {
            int s = 2 * j + (w >> 2);
            int rin = (w & 3) * 8 + (lane >> 3);
            int row = s * 64 + nh * 32 + rin;
            int g = (lane & 7) ^ (row & 7);
            gld_lds16((const char*)(Bb + (bcol + row) * (long)Ktot + (long)kt * 64) + g * 16,
                      (char*)lds + buf * 65536 + 32768 + j * 16384 + (w >> 2) * 8192 +
                          nh * 4096 + (w & 3) * 1024 + lane * 16);
        }
    };

    const int wr = w >> 2, wc = w & 3;          // 2 x 4 wave grid (128 x 64 out)
    const int fr = lane & 15, fq = lane >> 4;
    f32x4 acc[8][4] = {};
    short8 af[4][2], bf[2][2][2];

    stageA(0, 0, 0); stageB(0, 0, 0); stageB(0, 0, 1); stageA(0, 0, 1);
    stageA(1, 1, 0); stageB(1, 1, 0); stageB(1, 1, 1); stageA(1, 1, 1);
    VM8;
    __builtin_amdgcn_s_barrier();

    for (int i = 0; i < 15; i++) {
        const int kn = 2 * i + 2;
        PHASE(0, 0, 0, 1, 0, {}, VMNONE)
        PHASE(0, 0, 1, 0, 1, { stageA(kn, 0, 0); stageB(kn, 0, 0); }, VMNONE)
        PHASE(0, 1, 0, 1, 2, { stageB(kn, 0, 1); }, VMNONE)
        PHASE(0, 1, 1, 0, 2, { stageA(kn, 0, 1); }, VM8)
        PHASE(1, 0, 0, 1, 0, {}, VMNONE)
        PHASE(1, 0, 1, 0, 1, { stageA(kn + 1, 1, 0); stageB(kn + 1, 1, 0); }, VMNONE)
        PHASE(1, 1, 0, 1, 2, { stageB(kn + 1, 1, 1); }, VMNONE)
        PHASE(1, 1, 1, 0, 2, { stageA(kn + 1, 1, 1); }, VM8)
    }
    PHASE(0, 0, 0, 1, 0, {}, VMNONE)
    PHASE(0, 0, 1, 0, 1, {}, VMNONE)
    PHASE(0, 1, 0, 1, 2, {}, VMNONE)
    PHASE(0, 1, 1, 0, 2, {}, VM0)
    PHASE(1, 0, 0, 1, 0, {}, VMNONE)
    PHASE(1, 0, 1, 0, 1, {}, VMNONE)
    PHASE(1, 1, 0, 1, 2, {}, VMNONE)
    PHASE(1, 1, 1, 0, 2, {}, VMNONE)

    // ---- epilogue: LDS bounce -> coalesced short8 stores ----
    // quarter qr = (wrq, mhq): rows brow + wrq*128 + mhq*64 + [0,64)
    float* ldsf = (float*)lds;   // [64][258] f32 = 66 KB
    for (int qr = 0; qr < 4; qr++) {
        const int wrq = qr >> 1, mhq = qr & 1;
        __builtin_amdgcn_s_barrier();
        if (wr == wrq) {
#pragma unroll
            for (int mp = 0; mp < 4; mp++)
#pragma unroll
                for (int n = 0; n < 4; n++) {
                    int cc = wc * 64 + (n >> 1) * 32 + (n & 1) * 16 + fr;
#pragma unroll
                    for (int r = 0; r < 4; r++)
                        ldsf[(mp * 16 + fq * 4 + r) * 258 + cc] = acc[mhq * 4 + mp][n][r];
                }
        }
        __builtin_amdgcn_s_barrier();
#pragma unroll
        for (int c8 = 0; c8 < 4; c8++) {
            const int l = c8 * 16 + (tid >> 5);
            const int c = (tid & 31) * 8;
            const long row = brow + wrq * 128 + mhq * 64 + l;
            const long col = bcol + c;
            float v[8];
#pragma unroll
            for (int j = 0; j < 8; j++) v[j] = ldsf[l * 258 + c + j];
            if (MODE == 0) {
                const float* bp = (col >> 11) == 0 ? b0 : (col >> 11) == 1 ? b1 : b2;
                const long bc = col & 2047;
                short8 ob;
#pragma unroll
                for (int j = 0; j < 8; j++) ob[j] = f2bf(v[j] + bp[bc + j]);
                const long slab = col >> 7;
                *(short8*)((short*)Cv + slab * (2048L * 128) + row * 128 + (col & 127)) = ob;
            } else if (MODE == 1) {
                short8 ob;
#pragma unroll
                for (int j = 0; j < 8; j++) ob[j] = f2bf(fmaxf(v[j] + b0[col + j], 0.f));
                *(short8*)((short*)Cv + row * 8192 + col) = ob;
            } else {
                short8 ob;
#pragma unroll
                for (int j = 0; j < 8; j++) ob[j] = f2bf(v[j]);
                *(short8*)((short*)Cv + (long)z * (2048L * 2048) + row * 2048 + col) = ob;
            }
        }
    }
}

// --- flash attention v8: 2-deep rings (80KB LDS -> 2 blocks/CU) + defer-max -
__global__ __launch_bounds__(512, 4) void attn_flash(const short* __restrict__ Q,
                                                     const short* __restrict__ Kc,
                                                     const short* __restrict__ VT,
                                                     short* __restrict__ O) {
    __shared__ short lds[40960];   // 80 KB
    const int tid = threadIdx.x, lane = tid & 63, w = tid >> 6;
    const int bid = blockIdx.x;
    const int vid = (bid & 7) * 32 + (bid >> 3);   // XCD-chunked swizzle
    const int h = vid >> 4, qt = vid & 15;
    const int fr = lane & 15, fq = lane >> 4;
    const long qbase = (long)qt * 128 + w * 16;
    const short* Qh = Q  + (long)h * N_TOK * DK;
    const short* Kh = Kc + (long)h * N_TOK * DK;
    const short* Vh = VT + (long)h * DK * N_TOK;
    short* Pw = lds + 32768 + w * 1024;

    short8 qf[4];
#pragma unroll
    for (int c = 0; c < 4; c++)
        qf[c] = *(const short8*)(Qh + (qbase + fr) * DK + c * 32 + fq * 8);

    float mrow = -1e30f, lrow = 0.f;
    f32x4 oacc[8] = {};
    const float C1 = 0.08838834764831845f * 1.4426950408889634f; // 1/sqrt(128)*log2e
    const float THR = 16.f;

    int wr_off[4], rd_off[2];
#pragma unroll
    for (int jc = 0; jc < 4; jc++)
        wr_off[jc] = (fr * 64 + jc * 16 + fq * 4) ^ ((fr & 7) << 3);
#pragma unroll
    for (int kc = 0; kc < 2; kc++)
        rd_off[kc] = (fr * 64 + kc * 32 + fq * 8) ^ ((fr & 7) << 3);
    int colKb[4], colVb[2];
#pragma unroll
    for (int c = 0; c < 4; c++) colKb[c] = (c * 64 + fq * 16) ^ ((fr & 7) << 4);
#pragma unroll
    for (int kc = 0; kc < 2; kc++) colVb[kc] = (kc * 64 + fq * 16) ^ ((fr & 7) << 4);

    auto stageK = [&](int kvt) {
        const int buf = kvt & 1;
        const char* Kg = (const char*)(Kh + (long)kvt * 64 * DK);
        char* Kd = (char*)lds + buf * 16384;
#pragma unroll
        for (int i = 0; i < 2; i++) {
            int a = (w * 2 + i) * 1024 + (lane << 4);
            int src = a ^ (((a >> 8) & 7) << 4);
            gld_lds16(Kg + src, Kd + (w * 2 + i) * 1024);
        }
    };
    auto stageV = [&](int kvt) {
        const int buf = kvt & 1;
        char* Vd = (char*)lds + 32768 + buf * 16384;
#pragma unroll
        for (int i = 0; i < 2; i++) {
            int a = (w * 2 + i) * 1024 + (lane << 4);
            int row = a >> 7;
            int inner = (a & 127) ^ ((row & 7) << 4);
            const char* src = (const char*)Vh + ((long)row * N_TOK + (long)kvt * 64) * 2 + inner;
            gld_lds16(src, Vd + (w * 2 + i) * 1024);
        }
    };

    const int NT = N_TOK / 64;   // 32
    stageK(0); stageV(0); stageK(1);
    asm volatile("s_waitcnt vmcnt(4)" ::: "memory");
    __builtin_amdgcn_s_barrier();
    __builtin_amdgcn_sched_barrier(0);

    for (int t = 0; t < NT; t++) {
        if (t > 0) {
            if (t == NT - 1) asm volatile("s_waitcnt vmcnt(2)" ::: "memory");
            else             asm volatile("s_waitcnt vmcnt(4)" ::: "memory");
            __builtin_amdgcn_sched_barrier(0);
        }
        const char* Kcb = (const char*)lds + (t & 1) * 16384;
        f32x4 s[4] = {};
#pragma unroll
        for (int jc = 0; jc < 4; jc++) {
            const char* rb = Kcb + (jc * 16 + fr) * 256;
#pragma unroll
            for (int c = 0; c < 4; c++) {
                short8 kf = *(const short8*)(rb + colKb[c]);
                s[jc] = __builtin_amdgcn_mfma_f32_16x16x32_bf16(kf, qf[c], s[jc], 0, 0, 0);
            }
        }

        float tm = -1e30f;
#pragma unroll
        for (int jc = 0; jc < 4; jc++)
#pragma unroll
            for (int r = 0; r < 4; r++) tm = fmaxf(tm, s[jc][r]);
        tm = fmaxf(tm, __shfl_xor(tm, 16));
        tm = fmaxf(tm, __shfl_xor(tm, 32));
        if (!__all(tm <= mrow + THR)) {
            float nm = fmaxf(mrow, tm);
            float resc = exp2f(C1 * (mrow - nm));
            mrow = nm;
            lrow *= resc;
#pragma unroll
            for (int f = 0; f < 8; f++)
#pragma unroll
                for (int r = 0; r < 4; r++) oacc[f][r] *= resc;
        }
        float sum = 0.f;
#pragma unroll
        for (int jc = 0; jc < 4; jc++)
#pragma unroll
            for (int r = 0; r < 4; r++) {
                float p = exp2f(C1 * (s[jc][r] - mrow));
                s[jc][r] = p;
                sum += p;
            }
        sum += __shfl_xor(sum, 16);
        sum += __shfl_xor(sum, 32);
        lrow += sum;

#pragma unroll
        for (int jc = 0; jc < 4; jc++) {
            s16x4 pk;
            pk[0] = f2bf(s[jc][0]); pk[1] = f2bf(s[jc][1]);
            pk[2] = f2bf(s[jc][2]); pk[3] = f2bf(s[jc][3]);
            *(s16x4*)(Pw + wr_off[jc]) = pk;
        }
        short8 pa[2];
#pragma unroll
        for (int kc = 0; kc < 2; kc++)
            pa[kc] = *(const short8*)(Pw + rd_off[kc]);

        if (t == NT - 1) asm volatile("s_waitcnt vmcnt(0)" ::: "memory");
        else             asm volatile("s_waitcnt vmcnt(2)" ::: "memory");
        __builtin_amdgcn_sched_barrier(0);
        __builtin_amdgcn_s_barrier();
        __builtin_amdgcn_sched_barrier(0);

        const char* Vcb = (const char*)lds + 32768 + (t & 1) * 16384;
#pragma unroll
        for (int f = 0; f < 8; f++) {
            const char* rb = Vcb + (f * 16 + fr) * 128;
#pragma unroll
            for (int kc = 0; kc < 2; kc++) {
                short8 vf = *(const short8*)(rb + colVb[kc]);
                oacc[f] = __builtin_amdgcn_mfma_f32_16x16x32_bf16(vf, pa[kc], oacc[f], 0, 0, 0);
            }
        }

        if (t + 1 < NT) stageV(t + 1);
        if (t + 2 < NT) stageK(t + 2);
    }

    const float inv = 1.f / lrow;
    const long row = qbase + fr;
#pragma unroll
    for (int f = 0; f < 8; f++) {
        s16x4 ob;
        ob[0] = f2bf(oacc[f][0] * inv); ob[1] = f2bf(oacc[f][1] * inv);
        ob[2] = f2bf(oacc[f][2] * inv); ob[3] = f2bf(oacc[f][3] * inv);
        *(s16x4*)(O + row * (long)DMODEL + h * DK + f * 16 + fq * 4) = ob;
    }
}

// -------- fused Add + LayerNorm (both operands bf16), writes bf16 -----------
__global__ __launch_bounds__(256) void add_ln1(const short* __restrict__ A,
                                               const short* __restrict__ B,
                                               const float* __restrict__ alpha,
                                               const float* __restrict__ beta,
                                               short* __restrict__ outbf) {
    const int row = blockIdx.x, t = threadIdx.x;
    const long base = (long)row * DMODEL;
    float x[8];
    float s = 0.f, q = 0.f;
#pragma unroll
    for (int i = 0; i < 2; i++) {
        long off = base + (long)(t + i * 256) * 4;
        s16x4 va = *(const s16x4*)(A + off);
        s16x4 vb = *(const s16x4*)(B + off);
#pragma unroll
        for (int j = 0; j < 4; j++) {
            float v = bf2f(va[j]) + bf2f(vb[j]);
            x[i * 4 + j] = v;
            s += v; q += v * v;
        }
    }
#pragma unroll
    for (int o = 1; o < 64; o <<= 1) { s += __shfl_xor(s, o); q += __shfl_xor(q, o); }
    __shared__ float red[8];
    if ((t & 63) == 0) { red[t >> 6] = s; red[4 + (t >> 6)] = q; }
    __syncthreads();
    s = red[0] + red[1] + red[2] + red[3];
    q = red[4] + red[5] + red[6] + red[7];
    const float mean = s * (1.f / DMODEL);
    const float var = q * (1.f / DMODEL) - mean * mean;
    const float rstd = rsqrtf(var + 1e-5f);
#pragma unroll
    for (int i = 0; i < 2; i++) {
        long off = base + (long)(t + i * 256) * 4;
        float4 al = *(const float4*)(alpha + off);
        float4 be = *(const float4*)(beta + off);
        float a[4] = { al.x, al.y, al.z, al.w };
        float b[4] = { be.x, be.y, be.z, be.w };
        s16x4 ob;
#pragma unroll
        for (int j = 0; j < 4; j++)
            ob[j] = f2bf((x[i * 4 + j] - mean) * rstd * a[j] + b[j]);
        *(s16x4*)(outbf + off) = ob;
    }
}

// ---- Add + LN2: h1 (bf16) + 4 bf16 split-K slabs + bias -> f32 out ---------
__global__ __launch_bounds__(256) void add_ln2_red(const short* __restrict__ H1,
                                                   const short* __restrict__ F4,
                                                   const float* __restrict__ b2,
                                                   const float* __restrict__ alpha,
                                                   const float* __restrict__ beta,
                                                   float* __restrict__ out) {
    const int row = blockIdx.x, t = threadIdx.x;
    const long base = (long)row * DMODEL;
    const long SL = (long)N_TOK * DMODEL;
    float x[8];
    float s = 0.f, q = 0.f;
#pragma unroll
    for (int i = 0; i < 2; i++) {
        long off = base + (long)(t + i * 256) * 4;
        int col = (t + i * 256) * 4;
        s16x4 a  = *(const s16x4*)(H1 + off);
        s16x4 f0 = *(const s16x4*)(F4 + off);
        s16x4 f1 = *(const s16x4*)(F4 + off + SL);
        s16x4 f2 = *(const s16x4*)(F4 + off + 2 * SL);
        s16x4 f3 = *(const s16x4*)(F4 + off + 3 * SL);
        float4 bb = *(const float4*)(b2 + col);
        float ba[4] = { bb.x, bb.y, bb.z, bb.w };
#pragma unroll
        for (int j = 0; j < 4; j++) {
            float v = bf2f(a[j]) + ba[j] + bf2f(f0[j]) + bf2f(f1[j]) + bf2f(f2[j]) + bf2f(f3[j]);
            x[i * 4 + j] = v;
            s += v; q += v * v;
        }
    }
#pragma unroll
    for (int o = 1; o < 64; o <<= 1) { s += __shfl_xor(s, o); q += __shfl_xor(q, o); }
    __shared__ float red[8];
    if ((t & 63) == 0) { red[t >> 6] = s; red[4 + (t >> 6)] = q; }
    __syncthreads();
    s = red[0] + red[1] + red[2] + red[3];
    q = red[4] + red[5] + red[6] + red[7];
    const float mean = s * (1.f / DMODEL);
    const float var = q * (1.f / DMODEL) - mean * mean;
    const float rstd = rsqrtf(var + 1e-5f);
#pragma unroll
    for (int i = 0; i < 2; i++) {
        long off = base + (long)(t + i * 256) * 4;
        float4 al = *(const float4*)(alpha + off);
        float4 be = *(const float4*)(beta + off);
        float a[4] = { al.x, al.y, al.z, al.w };
        float b[4] = { be.x, be.y, be.z, be.w };
#pragma unroll
        for (int j = 0; j < 4; j++)
            out[off + j] = (x[i * 4 + j] - mean) * rstd * a[j] + b[j];
    }
}

extern "C" void kernel_launch(void* const* d_in, const int* in_sizes, int n_in,
                              void* d_out, int out_size, void* d_ws, size_t ws_size,
                              hipStream_t stream) {
    const float* X      = (const float*)d_in[0];
    const float* Wq     = (const float*)d_in[1];
    const float* bq     = (const float*)d_in[2];
    const float* Wk     = (const float*)d_in[3];
    const float* bk     = (const float*)d_in[4];
    const float* Wv     = (const float*)d_in[5];
    const float* bv     = (const float*)d_in[6];
    const float* alpha1 = (const float*)d_in[7];
    const float* beta1  = (const float*)d_in[8];
    const float* W1     = (const float*)d_in[9];
    const float* b1     = (const float*)d_in[10];
    const float* W2     = (const float*)d_in[11];
    const float* b2     = (const float*)d_in[12];
    const float* alpha2 = (const float*)d_in[13];
    const float* beta2  = (const float*)d_in[14];
    float* out = (float*)d_out;

    char* ws = (char*)d_ws;
    size_t off = 0;
    auto alloc = [&](size_t bytes) -> void* {
        void* p = ws + off;
        off += (bytes + 255) & ~(size_t)255;
        return p;
    };
    short* XBF   = (short*)alloc(2048UL * 2048 * 2);       // dead after add_ln1
    short* WQKVT = (short*)alloc(48UL * 128 * 2048 * 2);   // dead after QKV
    short* W1T   = (short*)alloc(8192UL * 2048 * 2);       // dead after FFN1
    short* W2T   = (short*)alloc(2048UL * 8192 * 2);
    short* QKV   = (short*)alloc(48UL * 2048 * 128 * 2);   // Q(0-15),K(16-31),V(32-47)
    short* VT    = (short*)alloc(16UL * 128 * 2048 * 2);
    short* ATTN  = (short*)alloc(2048UL * 2048 * 2);       // bf16
    short* H1BF  = (short*)alloc(2048UL * 2048 * 2);
    short* G     = (short*)alloc(2048UL * 8192 * 2);
    // F4 (32 MB, 4 bf16 split-K slabs) aliases XBF+WQKVT (both dead by FFN2)
    short* F4 = XBF;

    // 1. casts / transposes
    cast_f32_bf16<<<2048, 256, 0, stream>>>(X, XBF, 2048 * 2048 / 8);
    transpose_cast<float><<<dim3(2, 32, 16), 256, 0, stream>>>(Wq, WQKVT,                    2048, 128, 2048L * 128, 128L * 2048);
    transpose_cast<float><<<dim3(2, 32, 16), 256, 0, stream>>>(Wk, WQKVT + 16L * 128 * 2048, 2048, 128, 2048L * 128, 128L * 2048);
    transpose_cast<float><<<dim3(2, 32, 16), 256, 0, stream>>>(Wv, WQKVT + 32L * 128 * 2048, 2048, 128, 2048L * 128, 128L * 2048);
    transpose_cast<float><<<dim3(128, 32, 1), 256, 0, stream>>>(W1, W1T, 2048, 8192, 0, 0);
    transpose_cast<float><<<dim3(32, 128, 1), 256, 0, stream>>>(W2, W2T, 8192, 2048, 0, 0);

    // 2. QKV fused GEMM: M=2048, N=6144 (TM=8, TN=24 -> 192 blocks)
    gemm256<0><<<192, 512, 0, stream>>>(XBF, WQKVT, QKV, bq, bk, bv, 2048, 8);

    // 3. V -> V^T per head
    transpose_cast<__hip_bfloat16><<<dim3(2, 32, 16), 256, 0, stream>>>(
        (const __hip_bfloat16*)(QKV + 32L * 2048 * 128), VT, 2048, 128, 2048L * 128, 128L * 2048);

    // 4. attention (256 blocks x 8 waves; 2-deep rings, 2 blocks/CU)
    attn_flash<<<256, 512, 0, stream>>>(QKV, QKV + 16L * 2048 * 128, VT, ATTN);

    // 5. Add & LN 1 (bf16 residual XBF + bf16 attn)
    add_ln1<<<2048, 256, 0, stream>>>(XBF, ATTN, alpha1, beta1, H1BF);

    // 6. FFN: FFN1 M=2048 N=8192 (256 blocks); FFN2 split-K=4 (256 blocks)
    gemm256<1><<<256, 512, 0, stream>>>(H1BF, W1T, G, b1, nullptr, nullptr, 2048, 8);
    gemm256<2><<<256, 512, 0, stream>>>(G, W2T, F4, nullptr, nullptr, nullptr, 8192, 8);

    // 7. Add + reduce + LN 2 -> output
    add_ln2_red<<<2048, 256, 0, stream>>>(H1BF, F4, b2, alpha2, beta2, out);
}

// Round 18
// 329.944 us; speedup vs baseline: 1.2203x; 1.0142x over previous
//
#include <hip/hip_runtime.h>
#include <hip/hip_bf16.h>

#define N_TOK 2048
#define DMODEL 2048
#define NH 16
#define DK 128
#define DFF 8192

typedef __attribute__((ext_vector_type(8))) short short8;
typedef __attribute__((ext_vector_type(4))) short s16x4;
typedef __attribute__((ext_vector_type(4))) float f32x4;
typedef __attribute__((ext_vector_type(2))) unsigned int u32x2;

__device__ __forceinline__ short f2bf(float f) {
    unsigned int x = __builtin_bit_cast(unsigned int, f);
    unsigned int r = (x + 0x7fffu + ((x >> 16) & 1u)) >> 16;
    return (short)r;
}
__device__ __forceinline__ float bf2f(short s) {
    unsigned int u = ((unsigned int)(unsigned short)s) << 16;
    return __builtin_bit_cast(float, u);
}
// pack two f32 -> u32 of 2 bf16 (TRUNCATING; compiler emits v_perm_b32)
__device__ __forceinline__ unsigned int pk2bf(float lo, float hi) {
    return (__builtin_bit_cast(unsigned int, lo) >> 16) |
           (__builtin_bit_cast(unsigned int, hi) & 0xFFFF0000u);
}

// ---------------- cast X (f32 -> bf16), 8 elems/thread ----------------
__global__ __launch_bounds__(256) void cast_f32_bf16(const float* __restrict__ in,
                                                     short* __restrict__ out, int n8) {
    int i = blockIdx.x * 256 + threadIdx.x;
    if (i >= n8) return;
    const float4* p = (const float4*)in + (size_t)i * 2;
    float4 a = p[0], b = p[1];
    short8 o;
    o[0] = f2bf(a.x); o[1] = f2bf(a.y); o[2] = f2bf(a.z); o[3] = f2bf(a.w);
    o[4] = f2bf(b.x); o[5] = f2bf(b.y); o[6] = f2bf(b.z); o[7] = f2bf(b.w);
    *(short8*)(out + (size_t)i * 8) = o;
}

// --- transpose + cast to bf16 (64x64 LDS tiles, 16B reads + short8 writes) --
template <typename TIN>
__global__ __launch_bounds__(256) void transpose_cast(const TIN* __restrict__ in,
                                                      short* __restrict__ out,
                                                      int R, int C, long sIn, long sOut) {
    __shared__ float t[64][65];
    in  += (long)blockIdx.z * sIn;
    out += (long)blockIdx.z * sOut;
    const int tid = threadIdx.x;
    long r0 = (long)blockIdx.y * 64, c0 = (long)blockIdx.x * 64;
    if constexpr (sizeof(TIN) == 4) {
#pragma unroll
        for (int i = 0; i < 4; i++) {
            int r = (tid >> 4) + i * 16;
            int c = (tid & 15) * 4;
            float4 v = *(const float4*)((const float*)in + (r0 + r) * (long)C + c0 + c);
            t[r][c + 0] = v.x; t[r][c + 1] = v.y; t[r][c + 2] = v.z; t[r][c + 3] = v.w;
        }
    } else {
#pragma unroll
        for (int i = 0; i < 2; i++) {
            int r = (tid >> 3) + i * 32;
            int c = (tid & 7) * 8;
            short8 v = *(const short8*)((const short*)in + (r0 + r) * (long)C + c0 + c);
#pragma unroll
            for (int j = 0; j < 8; j++) t[r][c + j] = bf2f(v[j]);
        }
    }
    __syncthreads();
#pragma unroll
    for (int p = 0; p < 2; p++) {
        int c = (tid >> 3) + p * 32;
        int r8 = (tid & 7) * 8;
        short8 v;
#pragma unroll
        for (int j = 0; j < 8; j++) v[j] = f2bf(t[r8 + j][c]);
        *(short8*)(out + (c0 + c) * (long)R + r0 + r8) = v;
    }
}

// ---------------- async global->LDS helper ----------------
__device__ __forceinline__ void gld_lds16(const void* g, void* l) {
    __builtin_amdgcn_global_load_lds(
        (const __attribute__((address_space(1))) void*)g,
        (__attribute__((address_space(3))) void*)l, 16, 0, 0);
}

// ======== 256x256 bf16 GEMM, BK=64, 8 waves, 8-phase, B-read-once ===========
// R16: epilogue LDS-bounced -> coalesced short8 C-stores
#define VM8 asm volatile("s_waitcnt vmcnt(8)" ::: "memory")
#define VM0 asm volatile("s_waitcnt vmcnt(0)" ::: "memory")
#define VMNONE ((void)0)

#define PHASE(BUF, MH, NHI, RA, RBNH, STAGE_STMT, VMSTMT)                       \
  {                                                                             \
    if (RA) {                                                                   \
      _Pragma("unroll") for (int mp = 0; mp < 4; mp++)                          \
        _Pragma("unroll") for (int kk = 0; kk < 2; kk++) {                      \
          int rowA = wr * 128 + (MH) * 64 + mp * 16 + fr;                       \
          af[mp][kk] = *(const short8*)((const char*)lds + (BUF) * 65536 +      \
                         rowA * 128 + (((kk * 4 + fq) ^ (rowA & 7)) << 4));     \
        }                                                                       \
    }                                                                           \
    if ((RBNH) < 2) {                                                           \
      _Pragma("unroll") for (int np = 0; np < 2; np++)                          \
        _Pragma("unroll") for (int kk = 0; kk < 2; kk++) {                      \
          int rowB = wc * 64 + (RBNH) * 32 + np * 16 + fr;                      \
          bf[(RBNH) & 1][np][kk] =                                              \
              *(const short8*)((const char*)lds + (BUF) * 65536 + 32768 +       \
                  rowB * 128 + (((kk * 4 + fq) ^ (rowB & 7)) << 4));            \
        }                                                                       \
    }                                                                           \
    STAGE_STMT;                                                                 \
    __builtin_amdgcn_s_barrier();                                               \
    __builtin_amdgcn_s_setprio(1);                                              \
    _Pragma("unroll") for (int mp = 0; mp < 4; mp++)                            \
      _Pragma("unroll") for (int np = 0; np < 2; np++)                          \
        _Pragma("unroll") for (int kk = 0; kk < 2; kk++)                        \
          acc[(MH) * 4 + mp][(NHI) * 2 + np] =                                  \
              __builtin_amdgcn_mfma_f32_16x16x32_bf16(                          \
                  af[mp][kk], bf[NHI][np][kk], acc[(MH) * 4 + mp][(NHI) * 2 + np],\
                  0, 0, 0);                                                     \
    __builtin_amdgcn_s_setprio(0);                                              \
    VMSTMT;                                                                     \
    __builtin_amdgcn_s_barrier();                                               \
  }

template <int MODE>
__global__ __launch_bounds__(512, 2) void gemm256(const short* __restrict__ A,
                                                  const short* __restrict__ Bt,
                                                  void* __restrict__ Cv,
                                                  const float* __restrict__ b0,
                                                  const float* __restrict__ b1,
                                                  const float* __restrict__ b2,
                                                  int Ktot, int TM) {
    __shared__ short lds[65536];   // 128 KB
    const int tid = threadIdx.x, lane = tid & 63, w = tid >> 6;
    const int T = gridDim.x, bid = blockIdx.x;
    const int vbid = (bid & 7) * (T >> 3) + (bid >> 3);   // XCD chunking
    const int mt = vbid % TM;
    const int rest = vbid / TM;
    int nt = rest, z = 0;
    if (MODE == 2) { nt = rest & 7; z = rest >> 3; }
    const long brow = (long)mt * 256, bcol = (long)nt * 256;
    const short* Ab = A + (MODE == 2 ? (long)z * 2048 : 0);
    const short* Bb = Bt + (MODE == 2 ? (long)z * 2048 : 0);

    auto stageA = [&](int kt, int buf, int mh) {
#pragma unroll
        for (int j = 0; j < 2; j++) {
            int row = mh * 64 + j * 128 + (tid >> 3);
            int g = (lane & 7) ^ (row & 7);
            gld_lds16((const char*)(Ab + (brow + row) * (long)Ktot + (long)kt * 64) + g * 16,
                      (char*)lds + buf * 65536 + mh * 8192 + j * 16384 + w * 1024 + lane * 16);
        }
    };
    auto stageB = [&](int kt, int buf, int nh) {
#pragma unroll
        for (int j = 0; j < 2; j++) {
            int s = 2 * j + (w >> 2);
            int rin = (w & 3) * 8 + (lane >> 3);
            int row = s * 64 + nh * 32 + rin;
            int g = (lane & 7) ^ (row & 7);
            gld_lds16((const char*)(Bb + (bcol + row) * (long)Ktot + (long)kt * 64) + g * 16,
                      (char*)lds + buf * 65536 + 32768 + j * 16384 + (w >> 2) * 8192 +
                          nh * 4096 + (w & 3) * 1024 + lane * 16);
        }
    };

    const int wr = w >> 2, wc = w & 3;          // 2 x 4 wave grid (128 x 64 out)
    const int fr = lane & 15, fq = lane >> 4;
    f32x4 acc[8][4] = {};
    short8 af[4][2], bf[2][2][2];

    stageA(0, 0, 0); stageB(0, 0, 0); stageB(0, 0, 1); stageA(0, 0, 1);
    stageA(1, 1, 0); stageB(1, 1, 0); stageB(1, 1, 1); stageA(1, 1, 1);
    VM8;
    __builtin_amdgcn_s_barrier();

    for (int i = 0; i < 15; i++) {
        const int kn = 2 * i + 2;
        PHASE(0, 0, 0, 1, 0, {}, VMNONE)
        PHASE(0, 0, 1, 0, 1, { stageA(kn, 0, 0); stageB(kn, 0, 0); }, VMNONE)
        PHASE(0, 1, 0, 1, 2, { stageB(kn, 0, 1); }, VMNONE)
        PHASE(0, 1, 1, 0, 2, { stageA(kn, 0, 1); }, VM8)
        PHASE(1, 0, 0, 1, 0, {}, VMNONE)
        PHASE(1, 0, 1, 0, 1, { stageA(kn + 1, 1, 0); stageB(kn + 1, 1, 0); }, VMNONE)
        PHASE(1, 1, 0, 1, 2, { stageB(kn + 1, 1, 1); }, VMNONE)
        PHASE(1, 1, 1, 0, 2, { stageA(kn + 1, 1, 1); }, VM8)
    }
    PHASE(0, 0, 0, 1, 0, {}, VMNONE)
    PHASE(0, 0, 1, 0, 1, {}, VMNONE)
    PHASE(0, 1, 0, 1, 2, {}, VMNONE)
    PHASE(0, 1, 1, 0, 2, {}, VM0)
    PHASE(1, 0, 0, 1, 0, {}, VMNONE)
    PHASE(1, 0, 1, 0, 1, {}, VMNONE)
    PHASE(1, 1, 0, 1, 2, {}, VMNONE)
    PHASE(1, 1, 1, 0, 2, {}, VMNONE)

    // ---- epilogue: LDS bounce -> coalesced short8 stores ----
    float* ldsf = (float*)lds;   // [64][258] f32
    for (int qr = 0; qr < 4; qr++) {
        const int wrq = qr >> 1, mhq = qr & 1;
        __builtin_amdgcn_s_barrier();
        if (wr == wrq) {
#pragma unroll
            for (int mp = 0; mp < 4; mp++)
#pragma unroll
                for (int n = 0; n < 4; n++) {
                    int cc = wc * 64 + (n >> 1) * 32 + (n & 1) * 16 + fr;
#pragma unroll
                    for (int r = 0; r < 4; r++)
                        ldsf[(mp * 16 + fq * 4 + r) * 258 + cc] = acc[mhq * 4 + mp][n][r];
                }
        }
        __builtin_amdgcn_s_barrier();
#pragma unroll
        for (int c8 = 0; c8 < 4; c8++) {
            const int l = c8 * 16 + (tid >> 5);
            const int c = (tid & 31) * 8;
            const long row = brow + wrq * 128 + mhq * 64 + l;
            const long col = bcol + c;
            float v[8];
#pragma unroll
            for (int j = 0; j < 8; j++) v[j] = ldsf[l * 258 + c + j];
            if (MODE == 0) {
                const float* bp = (col >> 11) == 0 ? b0 : (col >> 11) == 1 ? b1 : b2;
                const long bc = col & 2047;
                short8 ob;
#pragma unroll
                for (int j = 0; j < 8; j++) ob[j] = f2bf(v[j] + bp[bc + j]);
                const long slab = col >> 7;
                *(short8*)((short*)Cv + slab * (2048L * 128) + row * 128 + (col & 127)) = ob;
            } else if (MODE == 1) {
                short8 ob;
#pragma unroll
                for (int j = 0; j < 8; j++) ob[j] = f2bf(fmaxf(v[j] + b0[col + j], 0.f));
                *(short8*)((short*)Cv + row * 8192 + col) = ob;
            } else {
                short8 ob;
#pragma unroll
                for (int j = 0; j < 8; j++) ob[j] = f2bf(v[j]);
                *(short8*)((short*)Cv + (long)z * (2048L * 2048) + row * 2048 + col) = ob;
            }
        }
    }
}

// --- flash attention v9: 2-deep rings + defer-max + VALU-trimmed softmax ----
__global__ __launch_bounds__(512, 4) void attn_flash(const short* __restrict__ Q,
                                                     const short* __restrict__ Kc,
                                                     const short* __restrict__ VT,
                                                     short* __restrict__ O) {
    __shared__ short lds[40960];   // 80 KB
    const int tid = threadIdx.x, lane = tid & 63, w = tid >> 6;
    const int bid = blockIdx.x;
    const int vid = (bid & 7) * 32 + (bid >> 3);   // XCD-chunked swizzle
    const int h = vid >> 4, qt = vid & 15;
    const int fr = lane & 15, fq = lane >> 4;
    const long qbase = (long)qt * 128 + w * 16;
    const short* Qh = Q  + (long)h * N_TOK * DK;
    const short* Kh = Kc + (long)h * N_TOK * DK;
    const short* Vh = VT + (long)h * DK * N_TOK;
    short* Pw = lds + 32768 + w * 1024;

    short8 qf[4];
#pragma unroll
    for (int c = 0; c < 4; c++)
        qf[c] = *(const short8*)(Qh + (qbase + fr) * DK + c * 32 + fq * 8);

    float mrow = -1e30f, lrow = 0.f;
    f32x4 oacc[8] = {};
    const float C1 = 0.08838834764831845f * 1.4426950408889634f; // 1/sqrt(128)*log2e
    const float THR = 16.f;
    float mc = C1 * mrow;   // cached C1*mrow for FMA-form exponent

    int wr_off[4], rd_off[2];
#pragma unroll
    for (int jc = 0; jc < 4; jc++)
        wr_off[jc] = (fr * 64 + jc * 16 + fq * 4) ^ ((fr & 7) << 3);
#pragma unroll
    for (int kc = 0; kc < 2; kc++)
        rd_off[kc] = (fr * 64 + kc * 32 + fq * 8) ^ ((fr & 7) << 3);
    int colKb[4], colVb[2];
#pragma unroll
    for (int c = 0; c < 4; c++) colKb[c] = (c * 64 + fq * 16) ^ ((fr & 7) << 4);
#pragma unroll
    for (int kc = 0; kc < 2; kc++) colVb[kc] = (kc * 64 + fq * 16) ^ ((fr & 7) << 4);

    auto stageK = [&](int kvt) {
        const int buf = kvt & 1;
        const char* Kg = (const char*)(Kh + (long)kvt * 64 * DK);
        char* Kd = (char*)lds + buf * 16384;
#pragma unroll
        for (int i = 0; i < 2; i++) {
            int a = (w * 2 + i) * 1024 + (lane << 4);
            int src = a ^ (((a >> 8) & 7) << 4);
            gld_lds16(Kg + src, Kd + (w * 2 + i) * 1024);
        }
    };
    auto stageV = [&](int kvt) {
        const int buf = kvt & 1;
        char* Vd = (char*)lds + 32768 + buf * 16384;
#pragma unroll
        for (int i = 0; i < 2; i++) {
            int a = (w * 2 + i) * 1024 + (lane << 4);
            int row = a >> 7;
            int inner = (a & 127) ^ ((row & 7) << 4);
            const char* src = (const char*)Vh + ((long)row * N_TOK + (long)kvt * 64) * 2 + inner;
            gld_lds16(src, Vd + (w * 2 + i) * 1024);
        }
    };

    const int NT = N_TOK / 64;   // 32
    stageK(0); stageV(0); stageK(1);
    asm volatile("s_waitcnt vmcnt(4)" ::: "memory");
    __builtin_amdgcn_s_barrier();
    __builtin_amdgcn_sched_barrier(0);

    for (int t = 0; t < NT; t++) {
        if (t > 0) {
            if (t == NT - 1) asm volatile("s_waitcnt vmcnt(2)" ::: "memory");
            else             asm volatile("s_waitcnt vmcnt(4)" ::: "memory");
            __builtin_amdgcn_sched_barrier(0);
        }
        const char* Kcb = (const char*)lds + (t & 1) * 16384;
        f32x4 s[4] = {};
#pragma unroll
        for (int jc = 0; jc < 4; jc++) {
            const char* rb = Kcb + (jc * 16 + fr) * 256;
#pragma unroll
            for (int c = 0; c < 4; c++) {
                short8 kf = *(const short8*)(rb + colKb[c]);
                s[jc] = __builtin_amdgcn_mfma_f32_16x16x32_bf16(kf, qf[c], s[jc], 0, 0, 0);
            }
        }

        // max via v_max3-friendly triples (15 ops -> ~8)
        float tm = fmaxf(fmaxf(s[0][0], s[0][1]), s[0][2]);
        tm = fmaxf(fmaxf(tm, s[0][3]), s[1][0]);
        tm = fmaxf(fmaxf(tm, s[1][1]), s[1][2]);
        tm = fmaxf(fmaxf(tm, s[1][3]), s[2][0]);
        tm = fmaxf(fmaxf(tm, s[2][1]), s[2][2]);
        tm = fmaxf(fmaxf(tm, s[2][3]), s[3][0]);
        tm = fmaxf(fmaxf(tm, s[3][1]), s[3][2]);
        tm = fmaxf(tm, s[3][3]);
        tm = fmaxf(tm, __shfl_xor(tm, 16));
        tm = fmaxf(tm, __shfl_xor(tm, 32));
        if (!__all(tm <= mrow + THR)) {
            float nm = fmaxf(mrow, tm);
            float resc = exp2f(C1 * (mrow - nm));
            mrow = nm;
            mc = C1 * mrow;
            lrow *= resc;
#pragma unroll
            for (int f = 0; f < 8; f++)
#pragma unroll
                for (int r = 0; r < 4; r++) oacc[f][r] *= resc;
        }
        // exp2(FMA) + immediate truncating pair-pack (v_perm)
        float sum = 0.f;
#pragma unroll
        for (int jc = 0; jc < 4; jc++) {
            float p0 = exp2f(fmaf(s[jc][0], C1, -mc));
            float p1 = exp2f(fmaf(s[jc][1], C1, -mc));
            float p2 = exp2f(fmaf(s[jc][2], C1, -mc));
            float p3 = exp2f(fmaf(s[jc][3], C1, -mc));
            sum += (p0 + p1) + (p2 + p3);
            u32x2 pk;
            pk[0] = pk2bf(p0, p1);
            pk[1] = pk2bf(p2, p3);
            *(u32x2*)(Pw + wr_off[jc]) = pk;
        }
        sum += __shfl_xor(sum, 16);
        sum += __shfl_xor(sum, 32);
        lrow += sum;

        short8 pa[2];
#pragma unroll
        for (int kc = 0; kc < 2; kc++)
            pa[kc] = *(const short8*)(Pw + rd_off[kc]);

        if (t == NT - 1) asm volatile("s_waitcnt vmcnt(0)" ::: "memory");
        else             asm volatile("s_waitcnt vmcnt(2)" ::: "memory");
        __builtin_amdgcn_sched_barrier(0);
        __builtin_amdgcn_s_barrier();
        __builtin_amdgcn_sched_barrier(0);

        const char* Vcb = (const char*)lds + 32768 + (t & 1) * 16384;
#pragma unroll
        for (int f = 0; f < 8; f++) {
            const char* rb = Vcb + (f * 16 + fr) * 128;
#pragma unroll
            for (int kc = 0; kc < 2; kc++) {
                short8 vf = *(const short8*)(rb + colVb[kc]);
                oacc[f] = __builtin_amdgcn_mfma_f32_16x16x32_bf16(vf, pa[kc], oacc[f], 0, 0, 0);
            }
        }

        if (t + 1 < NT) stageV(t + 1);
        if (t + 2 < NT) stageK(t + 2);
    }

    const float inv = 1.f / lrow;
    const long row = qbase + fr;
#pragma unroll
    for (int f = 0; f < 8; f++) {
        s16x4 ob;
        ob[0] = f2bf(oacc[f][0] * inv); ob[1] = f2bf(oacc[f][1] * inv);
        ob[2] = f2bf(oacc[f][2] * inv); ob[3] = f2bf(oacc[f][3] * inv);
        *(s16x4*)(O + row * (long)DMODEL + h * DK + f * 16 + fq * 4) = ob;
    }
}

// -------- fused Add + LayerNorm (both operands bf16), writes bf16 -----------
__global__ __launch_bounds__(256) void add_ln1(const short* __restrict__ A,
                                               const short* __restrict__ B,
                                               const float* __restrict__ alpha,
                                               const float* __restrict__ beta,
                                               short* __restrict__ outbf) {
    const int row = blockIdx.x, t = threadIdx.x;
    const long base = (long)row * DMODEL;
    float x[8];
    float s = 0.f, q = 0.f;
#pragma unroll
    for (int i = 0; i < 2; i++) {
        long off = base + (long)(t + i * 256) * 4;
        s16x4 va = *(const s16x4*)(A + off);
        s16x4 vb = *(const s16x4*)(B + off);
#pragma unroll
        for (int j = 0; j < 4; j++) {
            float v = bf2f(va[j]) + bf2f(vb[j]);
            x[i * 4 + j] = v;
            s += v; q += v * v;
        }
    }
#pragma unroll
    for (int o = 1; o < 64; o <<= 1) { s += __shfl_xor(s, o); q += __shfl_xor(q, o); }
    __shared__ float red[8];
    if ((t & 63) == 0) { red[t >> 6] = s; red[4 + (t >> 6)] = q; }
    __syncthreads();
    s = red[0] + red[1] + red[2] + red[3];
    q = red[4] + red[5] + red[6] + red[7];
    const float mean = s * (1.f / DMODEL);
    const float var = q * (1.f / DMODEL) - mean * mean;
    const float rstd = rsqrtf(var + 1e-5f);
#pragma unroll
    for (int i = 0; i < 2; i++) {
        long off = base + (long)(t + i * 256) * 4;
        float4 al = *(const float4*)(alpha + off);
        float4 be = *(const float4*)(beta + off);
        float a[4] = { al.x, al.y, al.z, al.w };
        float b[4] = { be.x, be.y, be.z, be.w };
        s16x4 ob;
#pragma unroll
        for (int j = 0; j < 4; j++)
            ob[j] = f2bf((x[i * 4 + j] - mean) * rstd * a[j] + b[j]);
        *(s16x4*)(outbf + off) = ob;
    }
}

// ---- Add + LN2: h1 (bf16) + 4 bf16 split-K slabs + bias -> f32 out ---------
__global__ __launch_bounds__(256) void add_ln2_red(const short* __restrict__ H1,
                                                   const short* __restrict__ F4,
                                                   const float* __restrict__ b2,
                                                   const float* __restrict__ alpha,
                                                   const float* __restrict__ beta,
                                                   float* __restrict__ out) {
    const int row = blockIdx.x, t = threadIdx.x;
    const long base = (long)row * DMODEL;
    const long SL = (long)N_TOK * DMODEL;
    float x[8];
    float s = 0.f, q = 0.f;
#pragma unroll
    for (int i = 0; i < 2; i++) {
        long off = base + (long)(t + i * 256) * 4;
        int col = (t + i * 256) * 4;
        s16x4 a  = *(const s16x4*)(H1 + off);
        s16x4 f0 = *(const s16x4*)(F4 + off);
        s16x4 f1 = *(const s16x4*)(F4 + off + SL);
        s16x4 f2 = *(const s16x4*)(F4 + off + 2 * SL);
        s16x4 f3 = *(const s16x4*)(F4 + off + 3 * SL);
        float4 bb = *(const float4*)(b2 + col);
        float ba[4] = { bb.x, bb.y, bb.z, bb.w };
#pragma unroll
        for (int j = 0; j < 4; j++) {
            float v = bf2f(a[j]) + ba[j] + bf2f(f0[j]) + bf2f(f1[j]) + bf2f(f2[j]) + bf2f(f3[j]);
            x[i * 4 + j] = v;
            s += v; q += v * v;
        }
    }
#pragma unroll
    for (int o = 1; o < 64; o <<= 1) { s += __shfl_xor(s, o); q += __shfl_xor(q, o); }
    __shared__ float red[8];
    if ((t & 63) == 0) { red[t >> 6] = s; red[4 + (t >> 6)] = q; }
    __syncthreads();
    s = red[0] + red[1] + red[2] + red[3];
    q = red[4] + red[5] + red[6] + red[7];
    const float mean = s * (1.f / DMODEL);
    const float var = q * (1.f / DMODEL) - mean * mean;
    const float rstd = rsqrtf(var + 1e-5f);
#pragma unroll
    for (int i = 0; i < 2; i++) {
        long off = base + (long)(t + i * 256) * 4;
        float4 al = *(const float4*)(alpha + off);
        float4 be = *(const float4*)(beta + off);
        float a[4] = { al.x, al.y, al.z, al.w };
        float b[4] = { be.x, be.y, be.z, be.w };
#pragma unroll
        for (int j = 0; j < 4; j++)
            out[off + j] = (x[i * 4 + j] - mean) * rstd * a[j] + b[j];
    }
}

extern "C" void kernel_launch(void* const* d_in, const int* in_sizes, int n_in,
                              void* d_out, int out_size, void* d_ws, size_t ws_size,
                              hipStream_t stream) {
    const float* X      = (const float*)d_in[0];
    const float* Wq     = (const float*)d_in[1];
    const float* bq     = (const float*)d_in[2];
    const float* Wk     = (const float*)d_in[3];
    const float* bk     = (const float*)d_in[4];
    const float* Wv     = (const float*)d_in[5];
    const float* bv     = (const float*)d_in[6];
    const float* alpha1 = (const float*)d_in[7];
    const float* beta1  = (const float*)d_in[8];
    const float* W1     = (const float*)d_in[9];
    const float* b1     = (const float*)d_in[10];
    const float* W2     = (const float*)d_in[11];
    const float* b2     = (const float*)d_in[12];
    const float* alpha2 = (const float*)d_in[13];
    const float* beta2  = (const float*)d_in[14];
    float* out = (float*)d_out;

    char* ws = (char*)d_ws;
    size_t off = 0;
    auto alloc = [&](size_t bytes) -> void* {
        void* p = ws + off;
        off += (bytes + 255) & ~(size_t)255;
        return p;
    };
    short* XBF   = (short*)alloc(2048UL * 2048 * 2);       // dead after add_ln1
    short* WQKVT = (short*)alloc(48UL * 128 * 2048 * 2);   // dead after QKV
    short* W1T   = (short*)alloc(8192UL * 2048 * 2);       // dead after FFN1
    short* W2T   = (short*)alloc(2048UL * 8192 * 2);
    short* QKV   = (short*)alloc(48UL * 2048 * 128 * 2);   // Q(0-15),K(16-31),V(32-47)
    short* VT    = (short*)alloc(16UL * 128 * 2048 * 2);
    short* ATTN  = (short*)alloc(2048UL * 2048 * 2);       // bf16
    short* H1BF  = (short*)alloc(2048UL * 2048 * 2);
    short* G     = (short*)alloc(2048UL * 8192 * 2);
    // F4 (32 MB, 4 bf16 split-K slabs) aliases XBF+WQKVT (both dead by FFN2)
    short* F4 = XBF;

    // 1. casts / transposes
    cast_f32_bf16<<<2048, 256, 0, stream>>>(X, XBF, 2048 * 2048 / 8);
    transpose_cast<float><<<dim3(2, 32, 16), 256, 0, stream>>>(Wq, WQKVT,                    2048, 128, 2048L * 128, 128L * 2048);
    transpose_cast<float><<<dim3(2, 32, 16), 256, 0, stream>>>(Wk, WQKVT + 16L * 128 * 2048, 2048, 128, 2048L * 128, 128L * 2048);
    transpose_cast<float><<<dim3(2, 32, 16), 256, 0, stream>>>(Wv, WQKVT + 32L * 128 * 2048, 2048, 128, 2048L * 128, 128L * 2048);
    transpose_cast<float><<<dim3(128, 32, 1), 256, 0, stream>>>(W1, W1T, 2048, 8192, 0, 0);
    transpose_cast<float><<<dim3(32, 128, 1), 256, 0, stream>>>(W2, W2T, 8192, 2048, 0, 0);

    // 2. QKV fused GEMM: M=2048, N=6144 (TM=8, TN=24 -> 192 blocks)
    gemm256<0><<<192, 512, 0, stream>>>(XBF, WQKVT, QKV, bq, bk, bv, 2048, 8);

    // 3. V -> V^T per head
    transpose_cast<__hip_bfloat16><<<dim3(2, 32, 16), 256, 0, stream>>>(
        (const __hip_bfloat16*)(QKV + 32L * 2048 * 128), VT, 2048, 128, 2048L * 128, 128L * 2048);

    // 4. attention (256 blocks x 8 waves; 2-deep rings, 2 blocks/CU)
    attn_flash<<<256, 512, 0, stream>>>(QKV, QKV + 16L * 2048 * 128, VT, ATTN);

    // 5. Add & LN 1 (bf16 residual XBF + bf16 attn)
    add_ln1<<<2048, 256, 0, stream>>>(XBF, ATTN, alpha1, beta1, H1BF);

    // 6. FFN: FFN1 M=2048 N=8192 (256 blocks); FFN2 split-K=4 (256 blocks)
    gemm256<1><<<256, 512, 0, stream>>>(H1BF, W1T, G, b1, nullptr, nullptr, 2048, 8);
    gemm256<2><<<256, 512, 0, stream>>>(G, W2T, F4, nullptr, nullptr, nullptr, 8192, 8);

    // 7. Add + reduce + LN 2 -> output
    add_ln2_red<<<2048, 256, 0, stream>>>(H1BF, F4, b2, alpha2, beta2, out);
}

// Round 19
// 327.360 us; speedup vs baseline: 1.2300x; 1.0079x over previous
//
#include <hip/hip_runtime.h>
#include <hip/hip_bf16.h>

#define N_TOK 2048
#define DMODEL 2048
#define NH 16
#define DK 128
#define DFF 8192

typedef __attribute__((ext_vector_type(8))) short short8;
typedef __attribute__((ext_vector_type(4))) short s16x4;
typedef __attribute__((ext_vector_type(4))) float f32x4;
typedef __attribute__((ext_vector_type(2))) unsigned int u32x2;

__device__ __forceinline__ short f2bf(float f) {
    unsigned int x = __builtin_bit_cast(unsigned int, f);
    unsigned int r = (x + 0x7fffu + ((x >> 16) & 1u)) >> 16;
    return (short)r;
}
__device__ __forceinline__ float bf2f(short s) {
    unsigned int u = ((unsigned int)(unsigned short)s) << 16;
    return __builtin_bit_cast(float, u);
}
// pack two f32 -> u32 of 2 bf16 (TRUNCATING; compiler emits v_perm_b32)
__device__ __forceinline__ unsigned int pk2bf(float lo, float hi) {
    return (__builtin_bit_cast(unsigned int, lo) >> 16) |
           (__builtin_bit_cast(unsigned int, hi) & 0xFFFF0000u);
}

// ---------------- cast X (f32 -> bf16), 8 elems/thread ----------------
__global__ __launch_bounds__(256) void cast_f32_bf16(const float* __restrict__ in,
                                                     short* __restrict__ out, int n8) {
    int i = blockIdx.x * 256 + threadIdx.x;
    if (i >= n8) return;
    const float4* p = (const float4*)in + (size_t)i * 2;
    float4 a = p[0], b = p[1];
    short8 o;
    o[0] = f2bf(a.x); o[1] = f2bf(a.y); o[2] = f2bf(a.z); o[3] = f2bf(a.w);
    o[4] = f2bf(b.x); o[5] = f2bf(b.y); o[6] = f2bf(b.z); o[7] = f2bf(b.w);
    *(short8*)(out + (size_t)i * 8) = o;
}

// --- transpose + cast to bf16 (64x64 LDS tiles, 16B reads + short8 writes) --
template <typename TIN>
__global__ __launch_bounds__(256) void transpose_cast(const TIN* __restrict__ in,
                                                      short* __restrict__ out,
                                                      int R, int C, long sIn, long sOut) {
    __shared__ float t[64][65];
    in  += (long)blockIdx.z * sIn;
    out += (long)blockIdx.z * sOut;
    const int tid = threadIdx.x;
    long r0 = (long)blockIdx.y * 64, c0 = (long)blockIdx.x * 64;
    if constexpr (sizeof(TIN) == 4) {
#pragma unroll
        for (int i = 0; i < 4; i++) {
            int r = (tid >> 4) + i * 16;
            int c = (tid & 15) * 4;
            float4 v = *(const float4*)((const float*)in + (r0 + r) * (long)C + c0 + c);
            t[r][c + 0] = v.x; t[r][c + 1] = v.y; t[r][c + 2] = v.z; t[r][c + 3] = v.w;
        }
    } else {
#pragma unroll
        for (int i = 0; i < 2; i++) {
            int r = (tid >> 3) + i * 32;
            int c = (tid & 7) * 8;
            short8 v = *(const short8*)((const short*)in + (r0 + r) * (long)C + c0 + c);
#pragma unroll
            for (int j = 0; j < 8; j++) t[r][c + j] = bf2f(v[j]);
        }
    }
    __syncthreads();
#pragma unroll
    for (int p = 0; p < 2; p++) {
        int c = (tid >> 3) + p * 32;
        int r8 = (tid & 7) * 8;
        short8 v;
#pragma unroll
        for (int j = 0; j < 8; j++) v[j] = f2bf(t[r8 + j][c]);
        *(short8*)(out + (c0 + c) * (long)R + r0 + r8) = v;
    }
}

// ---------------- async global->LDS helper ----------------
__device__ __forceinline__ void gld_lds16(const void* g, void* l) {
    __builtin_amdgcn_global_load_lds(
        (const __attribute__((address_space(1))) void*)g,
        (__attribute__((address_space(3))) void*)l, 16, 0, 0);
}

// ======== 256x256 bf16 GEMM, BK=64, 8 waves, 8-phase, B-read-once ===========
// Epilogue LDS-bounced; MODE 0 V-columns (bcol>=4096) write VT transposed.
#define VM8 asm volatile("s_waitcnt vmcnt(8)" ::: "memory")
#define VM0 asm volatile("s_waitcnt vmcnt(0)" ::: "memory")
#define VMNONE ((void)0)

#define PHASE(BUF, MH, NHI, RA, RBNH, STAGE_STMT, VMSTMT)                       \
  {                                                                             \
    if (RA) {                                                                   \
      _Pragma("unroll") for (int mp = 0; mp < 4; mp++)                          \
        _Pragma("unroll") for (int kk = 0; kk < 2; kk++) {                      \
          int rowA = wr * 128 + (MH) * 64 + mp * 16 + fr;                       \
          af[mp][kk] = *(const short8*)((const char*)lds + (BUF) * 65536 +      \
                         rowA * 128 + (((kk * 4 + fq) ^ (rowA & 7)) << 4));     \
        }                                                                       \
    }                                                                           \
    if ((RBNH) < 2) {                                                           \
      _Pragma("unroll") for (int np = 0; np < 2; np++)                          \
        _Pragma("unroll") for (int kk = 0; kk < 2; kk++) {                      \
          int rowB = wc * 64 + (RBNH) * 32 + np * 16 + fr;                      \
          bf[(RBNH) & 1][np][kk] =                                              \
              *(const short8*)((const char*)lds + (BUF) * 65536 + 32768 +       \
                  rowB * 128 + (((kk * 4 + fq) ^ (rowB & 7)) << 4));            \
        }                                                                       \
    }                                                                           \
    STAGE_STMT;                                                                 \
    __builtin_amdgcn_s_barrier();                                               \
    __builtin_amdgcn_s_setprio(1);                                              \
    _Pragma("unroll") for (int mp = 0; mp < 4; mp++)                            \
      _Pragma("unroll") for (int np = 0; np < 2; np++)                          \
        _Pragma("unroll") for (int kk = 0; kk < 2; kk++)                        \
          acc[(MH) * 4 + mp][(NHI) * 2 + np] =                                  \
              __builtin_amdgcn_mfma_f32_16x16x32_bf16(                          \
                  af[mp][kk], bf[NHI][np][kk], acc[(MH) * 4 + mp][(NHI) * 2 + np],\
                  0, 0, 0);                                                     \
    __builtin_amdgcn_s_setprio(0);                                              \
    VMSTMT;                                                                     \
    __builtin_amdgcn_s_barrier();                                               \
  }

template <int MODE>
__global__ __launch_bounds__(512, 2) void gemm256(const short* __restrict__ A,
                                                  const short* __restrict__ Bt,
                                                  void* __restrict__ Cv,
                                                  short* __restrict__ VTout,
                                                  const float* __restrict__ b0,
                                                  const float* __restrict__ b1,
                                                  const float* __restrict__ b2,
                                                  int Ktot, int TM) {
    __shared__ short lds[65536];   // 128 KB
    const int tid = threadIdx.x, lane = tid & 63, w = tid >> 6;
    const int T = gridDim.x, bid = blockIdx.x;
    const int vbid = (bid & 7) * (T >> 3) + (bid >> 3);   // XCD chunking
    const int mt = vbid % TM;
    const int rest = vbid / TM;
    int nt = rest, z = 0;
    if (MODE == 2) { nt = rest & 7; z = rest >> 3; }
    const long brow = (long)mt * 256, bcol = (long)nt * 256;
    const short* Ab = A + (MODE == 2 ? (long)z * 2048 : 0);
    const short* Bb = Bt + (MODE == 2 ? (long)z * 2048 : 0);

    auto stageA = [&](int kt, int buf, int mh) {
#pragma unroll
        for (int j = 0; j < 2; j++) {
            int row = mh * 64 + j * 128 + (tid >> 3);
            int g = (lane & 7) ^ (row & 7);
            gld_lds16((const char*)(Ab + (brow + row) * (long)Ktot + (long)kt * 64) + g * 16,
                      (char*)lds + buf * 65536 + mh * 8192 + j * 16384 + w * 1024 + lane * 16);
        }
    };
    auto stageB = [&](int kt, int buf, int nh) {
#pragma unroll
        for (int j = 0; j < 2; j++) {
            int s = 2 * j + (w >> 2);
            int rin = (w & 3) * 8 + (lane >> 3);
            int row = s * 64 + nh * 32 + rin;
            int g = (lane & 7) ^ (row & 7);
            gld_lds16((const char*)(Bb + (bcol + row) * (long)Ktot + (long)kt * 64) + g * 16,
                      (char*)lds + buf * 65536 + 32768 + j * 16384 + (w >> 2) * 8192 +
                          nh * 4096 + (w & 3) * 1024 + lane * 16);
        }
    };

    const int wr = w >> 2, wc = w & 3;          // 2 x 4 wave grid (128 x 64 out)
    const int fr = lane & 15, fq = lane >> 4;
    f32x4 acc[8][4] = {};
    short8 af[4][2], bf[2][2][2];

    stageA(0, 0, 0); stageB(0, 0, 0); stageB(0, 0, 1); stageA(0, 0, 1);
    stageA(1, 1, 0); stageB(1, 1, 0); stageB(1, 1, 1); stageA(1, 1, 1);
    VM8;
    __builtin_amdgcn_s_barrier();

    for (int i = 0; i < 15; i++) {
        const int kn = 2 * i + 2;
        PHASE(0, 0, 0, 1, 0, {}, VMNONE)
        PHASE(0, 0, 1, 0, 1, { stageA(kn, 0, 0); stageB(kn, 0, 0); }, VMNONE)
        PHASE(0, 1, 0, 1, 2, { stageB(kn, 0, 1); }, VMNONE)
        PHASE(0, 1, 1, 0, 2, { stageA(kn, 0, 1); }, VM8)
        PHASE(1, 0, 0, 1, 0, {}, VMNONE)
        PHASE(1, 0, 1, 0, 1, { stageA(kn + 1, 1, 0); stageB(kn + 1, 1, 0); }, VMNONE)
        PHASE(1, 1, 0, 1, 2, { stageB(kn + 1, 1, 1); }, VMNONE)
        PHASE(1, 1, 1, 0, 2, { stageA(kn + 1, 1, 1); }, VM8)
    }
    PHASE(0, 0, 0, 1, 0, {}, VMNONE)
    PHASE(0, 0, 1, 0, 1, {}, VMNONE)
    PHASE(0, 1, 0, 1, 2, {}, VMNONE)
    PHASE(0, 1, 1, 0, 2, {}, VM0)
    PHASE(1, 0, 0, 1, 0, {}, VMNONE)
    PHASE(1, 0, 1, 0, 1, {}, VMNONE)
    PHASE(1, 1, 0, 1, 2, {}, VMNONE)
    PHASE(1, 1, 1, 0, 2, {}, VMNONE)

    // ---- epilogue: LDS bounce -> coalesced stores ----
    float* ldsf = (float*)lds;   // [64][258] f32
    for (int qr = 0; qr < 4; qr++) {
        const int wrq = qr >> 1, mhq = qr & 1;
        __builtin_amdgcn_s_barrier();
        if (wr == wrq) {
#pragma unroll
            for (int mp = 0; mp < 4; mp++)
#pragma unroll
                for (int n = 0; n < 4; n++) {
                    int cc = wc * 64 + (n >> 1) * 32 + (n & 1) * 16 + fr;
#pragma unroll
                    for (int r = 0; r < 4; r++)
                        ldsf[(mp * 16 + fq * 4 + r) * 258 + cc] = acc[mhq * 4 + mp][n][r];
                }
        }
        __builtin_amdgcn_s_barrier();
        const long rq0 = brow + wrq * 128 + mhq * 64;
        if (MODE == 0 && bcol >= 4096) {
            // V quarter: bias + TRANSPOSED write into VT[hd][n] (16B/lane)
#pragma unroll
            for (int g = 0; g < 4; g++) {
                const int c = tid & 255;
                const int rg = (tid >> 8) + g * 2;        // 0..7
                const long col = bcol + c;
                const float bvv = b2[col & 2047];
                const long hd = col - 4096;               // 0..2047 -> VT row
                short8 ob;
#pragma unroll
                for (int j = 0; j < 8; j++)
                    ob[j] = f2bf(ldsf[(rg * 8 + j) * 258 + c] + bvv);
                *(short8*)(VTout + hd * (long)N_TOK + rq0 + rg * 8) = ob;
            }
        } else {
#pragma unroll
            for (int c8 = 0; c8 < 4; c8++) {
                const int l = c8 * 16 + (tid >> 5);
                const int c = (tid & 31) * 8;
                const long row = rq0 + l;
                const long col = bcol + c;
                float v[8];
#pragma unroll
                for (int j = 0; j < 8; j++) v[j] = ldsf[l * 258 + c + j];
                if (MODE == 0) {
                    const float* bp = (col >> 11) == 0 ? b0 : b1;
                    const long bc = col & 2047;
                    short8 ob;
#pragma unroll
                    for (int j = 0; j < 8; j++) ob[j] = f2bf(v[j] + bp[bc + j]);
                    const long slab = col >> 7;
                    *(short8*)((short*)Cv + slab * (2048L * 128) + row * 128 + (col & 127)) = ob;
                } else if (MODE == 1) {
                    short8 ob;
#pragma unroll
                    for (int j = 0; j < 8; j++) ob[j] = f2bf(fmaxf(v[j] + b0[col + j], 0.f));
                    *(short8*)((short*)Cv + row * 8192 + col) = ob;
                } else {
                    short8 ob;
#pragma unroll
                    for (int j = 0; j < 8; j++) ob[j] = f2bf(v[j]);
                    *(short8*)((short*)Cv + (long)z * (2048L * 2048) + row * 2048 + col) = ob;
                }
            }
        }
    }
}

// --- flash attention v9: 2-deep rings + defer-max + VALU-trimmed softmax ----
__global__ __launch_bounds__(512, 4) void attn_flash(const short* __restrict__ Q,
                                                     const short* __restrict__ Kc,
                                                     const short* __restrict__ VT,
                                                     short* __restrict__ O) {
    __shared__ short lds[40960];   // 80 KB
    const int tid = threadIdx.x, lane = tid & 63, w = tid >> 6;
    const int bid = blockIdx.x;
    const int vid = (bid & 7) * 32 + (bid >> 3);   // XCD-chunked swizzle
    const int h = vid >> 4, qt = vid & 15;
    const int fr = lane & 15, fq = lane >> 4;
    const long qbase = (long)qt * 128 + w * 16;
    const short* Qh = Q  + (long)h * N_TOK * DK;
    const short* Kh = Kc + (long)h * N_TOK * DK;
    const short* Vh = VT + (long)h * DK * N_TOK;
    short* Pw = lds + 32768 + w * 1024;

    short8 qf[4];
#pragma unroll
    for (int c = 0; c < 4; c++)
        qf[c] = *(const short8*)(Qh + (qbase + fr) * DK + c * 32 + fq * 8);

    float mrow = -1e30f, lrow = 0.f;
    f32x4 oacc[8] = {};
    const float C1 = 0.08838834764831845f * 1.4426950408889634f; // 1/sqrt(128)*log2e
    const float THR = 16.f;
    float mc = C1 * mrow;

    int wr_off[4], rd_off[2];
#pragma unroll
    for (int jc = 0; jc < 4; jc++)
        wr_off[jc] = (fr * 64 + jc * 16 + fq * 4) ^ ((fr & 7) << 3);
#pragma unroll
    for (int kc = 0; kc < 2; kc++)
        rd_off[kc] = (fr * 64 + kc * 32 + fq * 8) ^ ((fr & 7) << 3);
    int colKb[4], colVb[2];
#pragma unroll
    for (int c = 0; c < 4; c++) colKb[c] = (c * 64 + fq * 16) ^ ((fr & 7) << 4);
#pragma unroll
    for (int kc = 0; kc < 2; kc++) colVb[kc] = (kc * 64 + fq * 16) ^ ((fr & 7) << 4);

    auto stageK = [&](int kvt) {
        const int buf = kvt & 1;
        const char* Kg = (const char*)(Kh + (long)kvt * 64 * DK);
        char* Kd = (char*)lds + buf * 16384;
#pragma unroll
        for (int i = 0; i < 2; i++) {
            int a = (w * 2 + i) * 1024 + (lane << 4);
            int src = a ^ (((a >> 8) & 7) << 4);
            gld_lds16(Kg + src, Kd + (w * 2 + i) * 1024);
        }
    };
    auto stageV = [&](int kvt) {
        const int buf = kvt & 1;
        char* Vd = (char*)lds + 32768 + buf * 16384;
#pragma unroll
        for (int i = 0; i < 2; i++) {
            int a = (w * 2 + i) * 1024 + (lane << 4);
            int row = a >> 7;
            int inner = (a & 127) ^ ((row & 7) << 4);
            const char* src = (const char*)Vh + ((long)row * N_TOK + (long)kvt * 64) * 2 + inner;
            gld_lds16(src, Vd + (w * 2 + i) * 1024);
        }
    };

    const int NT = N_TOK / 64;   // 32
    stageK(0); stageV(0); stageK(1);
    asm volatile("s_waitcnt vmcnt(4)" ::: "memory");
    __builtin_amdgcn_s_barrier();
    __builtin_amdgcn_sched_barrier(0);

    for (int t = 0; t < NT; t++) {
        if (t > 0) {
            if (t == NT - 1) asm volatile("s_waitcnt vmcnt(2)" ::: "memory");
            else             asm volatile("s_waitcnt vmcnt(4)" ::: "memory");
            __builtin_amdgcn_sched_barrier(0);
        }
        const char* Kcb = (const char*)lds + (t & 1) * 16384;
        f32x4 s[4] = {};
#pragma unroll
        for (int jc = 0; jc < 4; jc++) {
            const char* rb = Kcb + (jc * 16 + fr) * 256;
#pragma unroll
            for (int c = 0; c < 4; c++) {
                short8 kf = *(const short8*)(rb + colKb[c]);
                s[jc] = __builtin_amdgcn_mfma_f32_16x16x32_bf16(kf, qf[c], s[jc], 0, 0, 0);
            }
        }

        float tm = fmaxf(fmaxf(s[0][0], s[0][1]), s[0][2]);
        tm = fmaxf(fmaxf(tm, s[0][3]), s[1][0]);
        tm = fmaxf(fmaxf(tm, s[1][1]), s[1][2]);
        tm = fmaxf(fmaxf(tm, s[1][3]), s[2][0]);
        tm = fmaxf(fmaxf(tm, s[2][1]), s[2][2]);
        tm = fmaxf(fmaxf(tm, s[2][3]), s[3][0]);
        tm = fmaxf(fmaxf(tm, s[3][1]), s[3][2]);
        tm = fmaxf(tm, s[3][3]);
        tm = fmaxf(tm, __shfl_xor(tm, 16));
        tm = fmaxf(tm, __shfl_xor(tm, 32));
        if (!__all(tm <= mrow + THR)) {
            float nm = fmaxf(mrow, tm);
            float resc = exp2f(C1 * (mrow - nm));
            mrow = nm;
            mc = C1 * mrow;
            lrow *= resc;
#pragma unroll
            for (int f = 0; f < 8; f++)
#pragma unroll
                for (int r = 0; r < 4; r++) oacc[f][r] *= resc;
        }
        float sum = 0.f;
#pragma unroll
        for (int jc = 0; jc < 4; jc++) {
            float p0 = exp2f(fmaf(s[jc][0], C1, -mc));
            float p1 = exp2f(fmaf(s[jc][1], C1, -mc));
            float p2 = exp2f(fmaf(s[jc][2], C1, -mc));
            float p3 = exp2f(fmaf(s[jc][3], C1, -mc));
            sum += (p0 + p1) + (p2 + p3);
            u32x2 pk;
            pk[0] = pk2bf(p0, p1);
            pk[1] = pk2bf(p2, p3);
            *(u32x2*)(Pw + wr_off[jc]) = pk;
        }
        sum += __shfl_xor(sum, 16);
        sum += __shfl_xor(sum, 32);
        lrow += sum;

        short8 pa[2];
#pragma unroll
        for (int kc = 0; kc < 2; kc++)
            pa[kc] = *(const short8*)(Pw + rd_off[kc]);

        if (t == NT - 1) asm volatile("s_waitcnt vmcnt(0)" ::: "memory");
        else             asm volatile("s_waitcnt vmcnt(2)" ::: "memory");
        __builtin_amdgcn_sched_barrier(0);
        __builtin_amdgcn_s_barrier();
        __builtin_amdgcn_sched_barrier(0);

        const char* Vcb = (const char*)lds + 32768 + (t & 1) * 16384;
#pragma unroll
        for (int f = 0; f < 8; f++) {
            const char* rb = Vcb + (f * 16 + fr) * 128;
#pragma unroll
            for (int kc = 0; kc < 2; kc++) {
                short8 vf = *(const short8*)(rb + colVb[kc]);
                oacc[f] = __builtin_amdgcn_mfma_f32_16x16x32_bf16(vf, pa[kc], oacc[f], 0, 0, 0);
            }
        }

        if (t + 1 < NT) stageV(t + 1);
        if (t + 2 < NT) stageK(t + 2);
    }

    const float inv = 1.f / lrow;
    const long row = qbase + fr;
#pragma unroll
    for (int f = 0; f < 8; f++) {
        s16x4 ob;
        ob[0] = f2bf(oacc[f][0] * inv); ob[1] = f2bf(oacc[f][1] * inv);
        ob[2] = f2bf(oacc[f][2] * inv); ob[3] = f2bf(oacc[f][3] * inv);
        *(s16x4*)(O + row * (long)DMODEL + h * DK + f * 16 + fq * 4) = ob;
    }
}

// -------- fused Add + LayerNorm (both operands bf16), writes bf16 -----------
__global__ __launch_bounds__(256) void add_ln1(const short* __restrict__ A,
                                               const short* __restrict__ B,
                                               const float* __restrict__ alpha,
                                               const float* __restrict__ beta,
                                               short* __restrict__ outbf) {
    const int row = blockIdx.x, t = threadIdx.x;
    const long base = (long)row * DMODEL;
    float x[8];
    float s = 0.f, q = 0.f;
#pragma unroll
    for (int i = 0; i < 2; i++) {
        long off = base + (long)(t + i * 256) * 4;
        s16x4 va = *(const s16x4*)(A + off);
        s16x4 vb = *(const s16x4*)(B + off);
#pragma unroll
        for (int j = 0; j < 4; j++) {
            float v = bf2f(va[j]) + bf2f(vb[j]);
            x[i * 4 + j] = v;
            s += v; q += v * v;
        }
    }
#pragma unroll
    for (int o = 1; o < 64; o <<= 1) { s += __shfl_xor(s, o); q += __shfl_xor(q, o); }
    __shared__ float red[8];
    if ((t & 63) == 0) { red[t >> 6] = s; red[4 + (t >> 6)] = q; }
    __syncthreads();
    s = red[0] + red[1] + red[2] + red[3];
    q = red[4] + red[5] + red[6] + red[7];
    const float mean = s * (1.f / DMODEL);
    const float var = q * (1.f / DMODEL) - mean * mean;
    const float rstd = rsqrtf(var + 1e-5f);
#pragma unroll
    for (int i = 0; i < 2; i++) {
        long off = base + (long)(t + i * 256) * 4;
        float4 al = *(const float4*)(alpha + off);
        float4 be = *(const float4*)(beta + off);
        float a[4] = { al.x, al.y, al.z, al.w };
        float b[4] = { be.x, be.y, be.z, be.w };
        s16x4 ob;
#pragma unroll
        for (int j = 0; j < 4; j++)
            ob[j] = f2bf((x[i * 4 + j] - mean) * rstd * a[j] + b[j]);
        *(s16x4*)(outbf + off) = ob;
    }
}

// ---- Add + LN2: h1 (bf16) + 4 bf16 split-K slabs + bias -> f32 out ---------
__global__ __launch_bounds__(256) void add_ln2_red(const short* __restrict__ H1,
                                                   const short* __restrict__ F4,
                                                   const float* __restrict__ b2,
                                                   const float* __restrict__ alpha,
                                                   const float* __restrict__ beta,
                                                   float* __restrict__ out) {
    const int row = blockIdx.x, t = threadIdx.x;
    const long base = (long)row * DMODEL;
    const long SL = (long)N_TOK * DMODEL;
    float x[8];
    float s = 0.f, q = 0.f;
#pragma unroll
    for (int i = 0; i < 2; i++) {
        long off = base + (long)(t + i * 256) * 4;
        int col = (t + i * 256) * 4;
        s16x4 a  = *(const s16x4*)(H1 + off);
        s16x4 f0 = *(const s16x4*)(F4 + off);
        s16x4 f1 = *(const s16x4*)(F4 + off + SL);
        s16x4 f2 = *(const s16x4*)(F4 + off + 2 * SL);
        s16x4 f3 = *(const s16x4*)(F4 + off + 3 * SL);
        float4 bb = *(const float4*)(b2 + col);
        float ba[4] = { bb.x, bb.y, bb.z, bb.w };
#pragma unroll
        for (int j = 0; j < 4; j++) {
            float v = bf2f(a[j]) + ba[j] + bf2f(f0[j]) + bf2f(f1[j]) + bf2f(f2[j]) + bf2f(f3[j]);
            x[i * 4 + j] = v;
            s += v; q += v * v;
        }
    }
#pragma unroll
    for (int o = 1; o < 64; o <<= 1) { s += __shfl_xor(s, o); q += __shfl_xor(q, o); }
    __shared__ float red[8];
    if ((t & 63) == 0) { red[t >> 6] = s; red[4 + (t >> 6)] = q; }
    __syncthreads();
    s = red[0] + red[1] + red[2] + red[3];
    q = red[4] + red[5] + red[6] + red[7];
    const float mean = s * (1.f / DMODEL);
    const float var = q * (1.f / DMODEL) - mean * mean;
    const float rstd = rsqrtf(var + 1e-5f);
#pragma unroll
    for (int i = 0; i < 2; i++) {
        long off = base + (long)(t + i * 256) * 4;
        float4 al = *(const float4*)(alpha + off);
        float4 be = *(const float4*)(beta + off);
        float a[4] = { al.x, al.y, al.z, al.w };
        float b[4] = { be.x, be.y, be.z, be.w };
#pragma unroll
        for (int j = 0; j < 4; j++)
            out[off + j] = (x[i * 4 + j] - mean) * rstd * a[j] + b[j];
    }
}

extern "C" void kernel_launch(void* const* d_in, const int* in_sizes, int n_in,
                              void* d_out, int out_size, void* d_ws, size_t ws_size,
                              hipStream_t stream) {
    const float* X      = (const float*)d_in[0];
    const float* Wq     = (const float*)d_in[1];
    const float* bq     = (const float*)d_in[2];
    const float* Wk     = (const float*)d_in[3];
    const float* bk     = (const float*)d_in[4];
    const float* Wv     = (const float*)d_in[5];
    const float* bv     = (const float*)d_in[6];
    const float* alpha1 = (const float*)d_in[7];
    const float* beta1  = (const float*)d_in[8];
    const float* W1     = (const float*)d_in[9];
    const float* b1     = (const float*)d_in[10];
    const float* W2     = (const float*)d_in[11];
    const float* b2     = (const float*)d_in[12];
    const float* alpha2 = (const float*)d_in[13];
    const float* beta2  = (const float*)d_in[14];
    float* out = (float*)d_out;

    char* ws = (char*)d_ws;
    size_t off = 0;
    auto alloc = [&](size_t bytes) -> void* {
        void* p = ws + off;
        off += (bytes + 255) & ~(size_t)255;
        return p;
    };
    short* XBF   = (short*)alloc(2048UL * 2048 * 2);       // dead after add_ln1
    short* WQKVT = (short*)alloc(48UL * 128 * 2048 * 2);   // dead after QKV
    short* W1T   = (short*)alloc(8192UL * 2048 * 2);       // dead after FFN1
    short* W2T   = (short*)alloc(2048UL * 8192 * 2);
    short* QKV   = (short*)alloc(48UL * 2048 * 128 * 2);   // Q(0-15),K(16-31); V slabs unused
    short* VT    = (short*)alloc(16UL * 128 * 2048 * 2);
    short* ATTN  = (short*)alloc(2048UL * 2048 * 2);       // bf16
    short* H1BF  = (short*)alloc(2048UL * 2048 * 2);
    short* G     = (short*)alloc(2048UL * 8192 * 2);
    // F4 (32 MB, 4 bf16 split-K slabs) aliases XBF+WQKVT (both dead by FFN2)
    short* F4 = XBF;

    // 1. casts / transposes
    cast_f32_bf16<<<2048, 256, 0, stream>>>(X, XBF, 2048 * 2048 / 8);
    transpose_cast<float><<<dim3(2, 32, 16), 256, 0, stream>>>(Wq, WQKVT,                    2048, 128, 2048L * 128, 128L * 2048);
    transpose_cast<float><<<dim3(2, 32, 16), 256, 0, stream>>>(Wk, WQKVT + 16L * 128 * 2048, 2048, 128, 2048L * 128, 128L * 2048);
    transpose_cast<float><<<dim3(2, 32, 16), 256, 0, stream>>>(Wv, WQKVT + 32L * 128 * 2048, 2048, 128, 2048L * 128, 128L * 2048);
    transpose_cast<float><<<dim3(128, 32, 1), 256, 0, stream>>>(W1, W1T, 2048, 8192, 0, 0);
    transpose_cast<float><<<dim3(32, 128, 1), 256, 0, stream>>>(W2, W2T, 8192, 2048, 0, 0);

    // 2. QKV fused GEMM: M=2048, N=6144; V columns written transposed -> VT
    gemm256<0><<<192, 512, 0, stream>>>(XBF, WQKVT, QKV, VT, bq, bk, bv, 2048, 8);

    // 3. attention (256 blocks x 8 waves; 2-deep rings, 2 blocks/CU)
    attn_flash<<<256, 512, 0, stream>>>(QKV, QKV + 16L * 2048 * 128, VT, ATTN);

    // 4. Add & LN 1 (bf16 residual XBF + bf16 attn)
    add_ln1<<<2048, 256, 0, stream>>>(XBF, ATTN, alpha1, beta1, H1BF);

    // 5. FFN: FFN1 M=2048 N=8192 (256 blocks); FFN2 split-K=4 (256 blocks)
    gemm256<1><<<256, 512, 0, stream>>>(H1BF, W1T, G, nullptr, b1, nullptr, nullptr, 2048, 8);
    gemm256<2><<<256, 512, 0, stream>>>(G, W2T, F4, nullptr, nullptr, nullptr, nullptr, 8192, 8);

    // 6. Add + reduce + LN 2 -> output
    add_ln2_red<<<2048, 256, 0, stream>>>(H1BF, F4, b2, alpha2, beta2, out);
}